// Round 1
// baseline (627.466 us; speedup 1.0000x reference)
//
#include <hip/hip_runtime.h>
#include <hip/hip_bf16.h>
#include <stdint.h>

#define T_SEQ 2048
#define H_DIM 3584
#define NQH 28
#define NKVH 4
#define HD 128
#define KV_N 512          // NKVH*HD
#define QKV_N 4608        // 3584 + 512 + 512
#define K_DIM 3584

typedef __bf16 bf16x8 __attribute__((ext_vector_type(8)));
typedef float f32x4 __attribute__((ext_vector_type(4)));

__device__ __forceinline__ ushort f2b(float f) {
  uint x = __builtin_bit_cast(uint, f);
  x += 0x7fffu + ((x >> 16) & 1u);
  return (ushort)(x >> 16);
}
__device__ __forceinline__ float b2f(ushort u) {
  return __builtin_bit_cast(float, (uint)u << 16);
}

__device__ __forceinline__ void gload_lds16(const void* gptr, void* ldsptr) {
  __builtin_amdgcn_global_load_lds(
      (const __attribute__((address_space(1))) uint32_t*)gptr,
      (__attribute__((address_space(3))) uint32_t*)ldsptr, 16, 0, 0);
}

// ---------------- cast hidden fp32 -> bf16 ----------------
__global__ void cast_bf16_kernel(const float* __restrict__ in, ushort* __restrict__ out) {
  int i = (blockIdx.x * 256 + threadIdx.x) * 4;
  float4 v = *(const float4*)(in + i);
  ushort4 o = make_ushort4(f2b(v.x), f2b(v.y), f2b(v.z), f2b(v.w));
  *(ushort4*)(out + i) = o;
}

// ---------------- transpose + cast: W (K x N) fp32 -> WT (N x K) bf16 ----------------
__global__ void transpose_cast_kernel(const float* __restrict__ W, ushort* __restrict__ WT,
                                      int K, int N) {
  __shared__ float tile[32][33];
  int n0 = blockIdx.x * 32, k0 = blockIdx.y * 32;
  int tx = threadIdx.x, ty = threadIdx.y;  // 32 x 8
#pragma unroll
  for (int j = 0; j < 4; ++j)
    tile[ty + j * 8][tx] = W[(size_t)(k0 + ty + j * 8) * N + n0 + tx];
  __syncthreads();
#pragma unroll
  for (int j = 0; j < 4; ++j)
    WT[(size_t)(n0 + ty + j * 8) * K + k0 + tx] = f2b(tile[tx][ty + j * 8]);
}

// ---------------- bias concat [bq | bk | bv] ----------------
__global__ void concat_bias_kernel(const float* __restrict__ bq, const float* __restrict__ bk,
                                   const float* __restrict__ bv, float* __restrict__ out) {
  int i = blockIdx.x * 256 + threadIdx.x;
  float v;
  if (i < H_DIM) v = bq[i];
  else if (i < H_DIM + KV_N) v = bk[i - H_DIM];
  else v = bv[i - H_DIM - KV_N];
  out[i] = v;
}

// ---------------- m97-style GEMM: C = A(MxK) @ B(KxN), BT given as (N x K) bf16 ----------------
// OUT_MODE 0: fp32 out, no bias.  OUT_MODE 1: bf16 out, +bias.
template <int OUT_MODE>
__global__ __launch_bounds__(256) void gemm_bt_kernel(
    const ushort* __restrict__ A, const ushort* __restrict__ BT,
    const float* __restrict__ bias, void* __restrict__ Cout, int M, int N, int K) {
  __shared__ ushort As[128 * 64];
  __shared__ ushort Bs[128 * 64];
  const int tid = threadIdx.x;
  const int lane = tid & 63;
  const int w = tid >> 6;
  const int wr = w >> 1, wc = w & 1;
  const int g4 = lane >> 4, l16 = lane & 15;
  const int r0 = blockIdx.y * 128, c0 = blockIdx.x * 128;
  const size_t rowbytes = (size_t)K * 2;

  f32x4 acc[4][4];
#pragma unroll
  for (int a = 0; a < 4; ++a)
#pragma unroll
    for (int b = 0; b < 4; ++b) acc[a][b] = f32x4{0.f, 0.f, 0.f, 0.f};

  for (int kt = 0; kt < K; kt += 64) {
#pragma unroll
    for (int j = 0; j < 4; ++j) {
      int b = (j * 256 + tid) * 16;  // byte index in 16KB tile
      int r = b >> 7;                // row (64 bf16 = 128B per row)
      int cb = b & 127;              // byte within row
      const char* ga = (const char*)A + (size_t)(r0 + r) * rowbytes + (size_t)kt * 2 + cb;
      gload_lds16(ga, (char*)As + j * 4096 + w * 1024);
      const char* gb = (const char*)BT + (size_t)(c0 + r) * rowbytes + (size_t)kt * 2 + cb;
      gload_lds16(gb, (char*)Bs + j * 4096 + w * 1024);
    }
    __syncthreads();
#pragma unroll
    for (int kk = 0; kk < 2; ++kk) {
      bf16x8 af[4], bfr[4];
#pragma unroll
      for (int mi = 0; mi < 4; ++mi) {
        int row = wr * 64 + mi * 16 + l16;
        af[mi] = *(const bf16x8*)((const char*)As + row * 128 + kk * 64 + g4 * 16);
      }
#pragma unroll
      for (int ni = 0; ni < 4; ++ni) {
        int row = wc * 64 + ni * 16 + l16;
        bfr[ni] = *(const bf16x8*)((const char*)Bs + row * 128 + kk * 64 + g4 * 16);
      }
#pragma unroll
      for (int mi = 0; mi < 4; ++mi)
#pragma unroll
        for (int ni = 0; ni < 4; ++ni)
          acc[mi][ni] = __builtin_amdgcn_mfma_f32_16x16x32_bf16(af[mi], bfr[ni], acc[mi][ni], 0, 0, 0);
    }
    __syncthreads();
  }
  // epilogue: D row=(lane>>4)*4+i, col=lane&15 (m89-verified layout)
#pragma unroll
  for (int mi = 0; mi < 4; ++mi) {
#pragma unroll
    for (int ni = 0; ni < 4; ++ni) {
      int col = c0 + wc * 64 + ni * 16 + l16;
      float bv = (OUT_MODE == 1) ? bias[col] : 0.f;
#pragma unroll
      for (int i = 0; i < 4; ++i) {
        int row = r0 + wr * 64 + mi * 16 + g4 * 4 + i;
        float v = acc[mi][ni][i] + bv;
        if (OUT_MODE == 1)
          ((ushort*)Cout)[(size_t)row * N + col] = f2b(v);
        else
          ((float*)Cout)[(size_t)row * N + col] = v;
      }
    }
  }
}

// ---------------- RoPE in-place on QKV (q heads 0..27, k heads 28..31) ----------------
__global__ void rope_kernel(ushort* __restrict__ QKV, const int* __restrict__ pos_ids) {
  int t = blockIdx.x;
  float pos = (float)pos_ids[t];
  ushort* row = QKV + (size_t)t * QKV_N;
  for (int p = threadIdx.x; p < 2048; p += 256) {  // 32 heads * 64 pairs
    int head = p >> 6;
    int d = p & 63;
    float inv = expf(-0.2158673524f * (float)d);  // theta^(-d/64), ln(1e6)/64
    float fr = pos * inv;
    float s, c;
    sincosf(fr, &s, &c);
    int c1 = head * 128 + d, c2 = c1 + 64;
    float x1 = b2f(row[c1]), x2 = b2f(row[c2]);
    row[c1] = f2b(x1 * c - x2 * s);
    row[c2] = f2b(x2 * c + x1 * s);
  }
}

// ---------------- build VT[kh][d][s] from QKV v-part ----------------
__global__ void build_vt_kernel(const ushort* __restrict__ QKV, ushort* __restrict__ VT) {
  __shared__ ushort tile[32][33];
  int kh = blockIdx.z;
  int d0 = blockIdx.x * 32, s0 = blockIdx.y * 32;
  int tx = threadIdx.x, ty = threadIdx.y;
#pragma unroll
  for (int j = 0; j < 4; ++j)
    tile[ty + j * 8][tx] =
        QKV[(size_t)(s0 + ty + j * 8) * QKV_N + (H_DIM + KV_N) + kh * 128 + d0 + tx];
  __syncthreads();
#pragma unroll
  for (int j = 0; j < 4; ++j)
    VT[((size_t)kh * 128 + d0 + ty + j * 8) * T_SEQ + s0 + tx] = tile[tx][ty + j * 8];
}

// ---------------- flash attention: 1 wave per (16 q-rows, head) ----------------
__global__ __launch_bounds__(64) void attn_kernel(const ushort* __restrict__ QKV,
                                                  const ushort* __restrict__ VT,
                                                  ushort* __restrict__ O) {
  __shared__ ushort P_lds[16 * 40];  // padded pitch 40 to break bank conflicts
  const int lane = threadIdx.x;
  const int qb = blockIdx.x;  // 0..127
  const int h = blockIdx.y;   // 0..27
  const int kh = h / 7;
  const int t0 = qb * 16;
  const int g4 = lane >> 4, l16 = lane & 15;

  // Q fragments (A-operand): lane holds Q[t0+l16][kk*32 + g4*8 + j]
  bf16x8 qf[4];
  const ushort* qrow = QKV + (size_t)(t0 + l16) * QKV_N + h * 128;
#pragma unroll
  for (int kk = 0; kk < 4; ++kk) qf[kk] = *(const bf16x8*)(qrow + kk * 32 + g4 * 8);

  f32x4 acc[8];
#pragma unroll
  for (int i = 0; i < 8; ++i) acc[i] = f32x4{0.f, 0.f, 0.f, 0.f};
  float m[4], lsum[4];
#pragma unroll
  for (int i = 0; i < 4; ++i) { m[i] = -3e38f; lsum[i] = 0.f; }

  const int nblk = (t0 + 15) / 32 + 1;
  const ushort* Kbase = QKV + (H_DIM) + kh * 128;
  const ushort* Vbase = VT + (size_t)kh * 128 * T_SEQ;

  for (int sb = 0; sb < nblk; ++sb) {
    const int s0 = sb * 32;
    // S (16 x 32) = Q @ K^T
    f32x4 sacc[2] = {f32x4{0.f, 0.f, 0.f, 0.f}, f32x4{0.f, 0.f, 0.f, 0.f}};
#pragma unroll
    for (int c = 0; c < 2; ++c) {
      const ushort* krow = Kbase + (size_t)(s0 + c * 16 + l16) * QKV_N;
#pragma unroll
      for (int kk = 0; kk < 4; ++kk) {
        bf16x8 kf = *(const bf16x8*)(krow + kk * 32 + g4 * 8);
        sacc[c] = __builtin_amdgcn_mfma_f32_16x16x32_bf16(qf[kk], kf, sacc[c], 0, 0, 0);
      }
    }
    // scale + causal mask + online softmax (row = g4*4+i, col = c*16+l16)
#pragma unroll
    for (int i = 0; i < 4; ++i) {
      int t = t0 + g4 * 4 + i;
#pragma unroll
      for (int c = 0; c < 2; ++c) {
        int s = s0 + c * 16 + l16;
        float v = sacc[c][i] * 0.08838834764831845f;
        sacc[c][i] = (s <= t) ? v : -1e30f;
      }
      float v = fmaxf(sacc[0][i], sacc[1][i]);
#pragma unroll
      for (int mk = 1; mk < 16; mk <<= 1) v = fmaxf(v, __shfl_xor(v, mk, 64));
      float mnew = fmaxf(m[i], v);
      float rescale = __expf(m[i] - mnew);
      m[i] = mnew;
      float ps = 0.f;
#pragma unroll
      for (int c = 0; c < 2; ++c) {
        float pv = __expf(sacc[c][i] - mnew);
        sacc[c][i] = pv;
        ps += pv;
      }
#pragma unroll
      for (int mk = 1; mk < 16; mk <<= 1) ps += __shfl_xor(ps, mk, 64);
      lsum[i] = lsum[i] * rescale + ps;
#pragma unroll
      for (int dc = 0; dc < 8; ++dc) acc[dc][i] *= rescale;
    }
    // P -> LDS (D-layout) then read back in A-layout
    __syncthreads();
#pragma unroll
    for (int i = 0; i < 4; ++i)
#pragma unroll
      for (int c = 0; c < 2; ++c)
        P_lds[(g4 * 4 + i) * 40 + c * 16 + l16] = f2b(sacc[c][i]);
    __syncthreads();
    bf16x8 pf = *(const bf16x8*)(P_lds + l16 * 40 + g4 * 8);
    // O += P @ V   (V via VT so B-operand reads are contiguous)
#pragma unroll
    for (int dc = 0; dc < 8; ++dc) {
      bf16x8 vf = *(const bf16x8*)(Vbase + (size_t)(dc * 16 + l16) * T_SEQ + s0 + g4 * 8);
      acc[dc] = __builtin_amdgcn_mfma_f32_16x16x32_bf16(pf, vf, acc[dc], 0, 0, 0);
    }
  }
  // epilogue
#pragma unroll
  for (int i = 0; i < 4; ++i) {
    float inv = 1.f / lsum[i];
    int t = t0 + g4 * 4 + i;
#pragma unroll
    for (int dc = 0; dc < 8; ++dc)
      O[(size_t)t * H_DIM + h * 128 + dc * 16 + l16] = f2b(acc[dc][i] * inv);
  }
}

extern "C" void kernel_launch(void* const* d_in, const int* in_sizes, int n_in,
                              void* d_out, int out_size, void* d_ws, size_t ws_size,
                              hipStream_t stream) {
  const float* hs = (const float*)d_in[0];
  const int* pos = (const int*)d_in[1];
  const float* Wq = (const float*)d_in[2];
  const float* bq = (const float*)d_in[3];
  const float* Wk = (const float*)d_in[4];
  const float* bk = (const float*)d_in[5];
  const float* Wv = (const float*)d_in[6];
  const float* bv = (const float*)d_in[7];
  const float* Wo = (const float*)d_in[8];
  float* out = (float*)d_out;

  char* p = (char*)d_ws;
  ushort* hs_b = (ushort*)p;  p += (size_t)T_SEQ * H_DIM * 2;
  ushort* WqkvT = (ushort*)p; p += (size_t)QKV_N * H_DIM * 2;
  ushort* WoT = (ushort*)p;   p += (size_t)H_DIM * H_DIM * 2;
  float* biasb = (float*)p;   p += (size_t)QKV_N * 4;
  ushort* QKV = (ushort*)p;   p += (size_t)T_SEQ * QKV_N * 2;
  ushort* VT = (ushort*)p;    p += (size_t)NKVH * HD * T_SEQ * 2;
  ushort* Obuf = (ushort*)p;  p += (size_t)T_SEQ * H_DIM * 2;

  cast_bf16_kernel<<<T_SEQ * H_DIM / 1024, 256, 0, stream>>>(hs, hs_b);
  transpose_cast_kernel<<<dim3(H_DIM / 32, H_DIM / 32), dim3(32, 8), 0, stream>>>(Wq, WqkvT, H_DIM, H_DIM);
  transpose_cast_kernel<<<dim3(KV_N / 32, H_DIM / 32), dim3(32, 8), 0, stream>>>(
      Wk, WqkvT + (size_t)H_DIM * H_DIM, H_DIM, KV_N);
  transpose_cast_kernel<<<dim3(KV_N / 32, H_DIM / 32), dim3(32, 8), 0, stream>>>(
      Wv, WqkvT + (size_t)(H_DIM + KV_N) * H_DIM, H_DIM, KV_N);
  transpose_cast_kernel<<<dim3(H_DIM / 32, H_DIM / 32), dim3(32, 8), 0, stream>>>(Wo, WoT, H_DIM, H_DIM);
  concat_bias_kernel<<<QKV_N / 256, 256, 0, stream>>>(bq, bk, bv, biasb);
  gemm_bt_kernel<1><<<dim3(QKV_N / 128, T_SEQ / 128), 256, 0, stream>>>(
      hs_b, WqkvT, biasb, QKV, T_SEQ, QKV_N, K_DIM);
  rope_kernel<<<T_SEQ, 256, 0, stream>>>(QKV, pos);
  build_vt_kernel<<<dim3(HD / 32, T_SEQ / 32, NKVH), dim3(32, 8), 0, stream>>>(QKV, VT);
  attn_kernel<<<dim3(T_SEQ / 16, NQH), 64, 0, stream>>>(QKV, VT, Obuf);
  gemm_bt_kernel<0><<<dim3(H_DIM / 128, T_SEQ / 128), 256, 0, stream>>>(
      Obuf, WoT, nullptr, out, T_SEQ, H_DIM, K_DIM);
}

// Round 2
// 455.537 us; speedup vs baseline: 1.3774x; 1.3774x over previous
//
#include <hip/hip_runtime.h>
#include <hip/hip_bf16.h>
#include <stdint.h>

#define T_SEQ 2048
#define H_DIM 3584
#define NQH 28
#define NKVH 4
#define HD 128
#define KV_N 512          // NKVH*HD
#define QKV_N 4608        // 3584 + 512 + 512
#define K_DIM 3584

typedef __bf16 bf16x8 __attribute__((ext_vector_type(8)));
typedef float f32x4 __attribute__((ext_vector_type(4)));

__device__ __forceinline__ ushort f2b(float f) {
  uint x = __builtin_bit_cast(uint, f);
  x += 0x7fffu + ((x >> 16) & 1u);
  return (ushort)(x >> 16);
}
__device__ __forceinline__ float b2f(ushort u) {
  return __builtin_bit_cast(float, (uint)u << 16);
}

__device__ __forceinline__ void gload_lds16(const void* gptr, void* ldsptr) {
  __builtin_amdgcn_global_load_lds(
      (const __attribute__((address_space(1))) uint32_t*)gptr,
      (__attribute__((address_space(3))) uint32_t*)ldsptr, 16, 0, 0);
}

// ---------------- cast hidden fp32 -> bf16 ----------------
__global__ void cast_bf16_kernel(const float* __restrict__ in, ushort* __restrict__ out) {
  int i = (blockIdx.x * 256 + threadIdx.x) * 4;
  float4 v = *(const float4*)(in + i);
  ushort4 o = make_ushort4(f2b(v.x), f2b(v.y), f2b(v.z), f2b(v.w));
  *(ushort4*)(out + i) = o;
}

// ---------------- transpose + cast: W (K x N) fp32 -> WT (N x K) bf16 ----------------
__global__ void transpose_cast_kernel(const float* __restrict__ W, ushort* __restrict__ WT,
                                      int K, int N) {
  __shared__ float tile[32][33];
  int n0 = blockIdx.x * 32, k0 = blockIdx.y * 32;
  int tx = threadIdx.x, ty = threadIdx.y;  // 32 x 8
#pragma unroll
  for (int j = 0; j < 4; ++j)
    tile[ty + j * 8][tx] = W[(size_t)(k0 + ty + j * 8) * N + n0 + tx];
  __syncthreads();
#pragma unroll
  for (int j = 0; j < 4; ++j)
    WT[(size_t)(n0 + ty + j * 8) * K + k0 + tx] = f2b(tile[tx][ty + j * 8]);
}

// ---------------- bias concat [bq | bk | bv] ----------------
__global__ void concat_bias_kernel(const float* __restrict__ bq, const float* __restrict__ bk,
                                   const float* __restrict__ bv, float* __restrict__ out) {
  int i = blockIdx.x * 256 + threadIdx.x;
  float v;
  if (i < H_DIM) v = bq[i];
  else if (i < H_DIM + KV_N) v = bk[i - H_DIM];
  else v = bv[i - H_DIM - KV_N];
  out[i] = v;
}

// ---------------- m97-style GEMM: C = A(MxK) @ B(KxN), BT given as (N x K) bf16 ----------------
template <int OUT_MODE>
__global__ __launch_bounds__(256) void gemm_bt_kernel(
    const ushort* __restrict__ A, const ushort* __restrict__ BT,
    const float* __restrict__ bias, void* __restrict__ Cout, int M, int N, int K) {
  __shared__ ushort As[128 * 64];
  __shared__ ushort Bs[128 * 64];
  const int tid = threadIdx.x;
  const int lane = tid & 63;
  const int w = tid >> 6;
  const int wr = w >> 1, wc = w & 1;
  const int g4 = lane >> 4, l16 = lane & 15;
  const int r0 = blockIdx.y * 128, c0 = blockIdx.x * 128;
  const size_t rowbytes = (size_t)K * 2;

  f32x4 acc[4][4];
#pragma unroll
  for (int a = 0; a < 4; ++a)
#pragma unroll
    for (int b = 0; b < 4; ++b) acc[a][b] = f32x4{0.f, 0.f, 0.f, 0.f};

  for (int kt = 0; kt < K; kt += 64) {
#pragma unroll
    for (int j = 0; j < 4; ++j) {
      int b = (j * 256 + tid) * 16;  // byte index in 16KB tile
      int r = b >> 7;                // row (64 bf16 = 128B per row)
      int cb = b & 127;              // byte within row
      const char* ga = (const char*)A + (size_t)(r0 + r) * rowbytes + (size_t)kt * 2 + cb;
      gload_lds16(ga, (char*)As + j * 4096 + w * 1024);
      const char* gb = (const char*)BT + (size_t)(c0 + r) * rowbytes + (size_t)kt * 2 + cb;
      gload_lds16(gb, (char*)Bs + j * 4096 + w * 1024);
    }
    __syncthreads();
#pragma unroll
    for (int kk = 0; kk < 2; ++kk) {
      bf16x8 af[4], bfr[4];
#pragma unroll
      for (int mi = 0; mi < 4; ++mi) {
        int row = wr * 64 + mi * 16 + l16;
        af[mi] = *(const bf16x8*)((const char*)As + row * 128 + kk * 64 + g4 * 16);
      }
#pragma unroll
      for (int ni = 0; ni < 4; ++ni) {
        int row = wc * 64 + ni * 16 + l16;
        bfr[ni] = *(const bf16x8*)((const char*)Bs + row * 128 + kk * 64 + g4 * 16);
      }
#pragma unroll
      for (int mi = 0; mi < 4; ++mi)
#pragma unroll
        for (int ni = 0; ni < 4; ++ni)
          acc[mi][ni] = __builtin_amdgcn_mfma_f32_16x16x32_bf16(af[mi], bfr[ni], acc[mi][ni], 0, 0, 0);
    }
    __syncthreads();
  }
#pragma unroll
  for (int mi = 0; mi < 4; ++mi) {
#pragma unroll
    for (int ni = 0; ni < 4; ++ni) {
      int col = c0 + wc * 64 + ni * 16 + l16;
      float bv = (OUT_MODE == 1) ? bias[col] : 0.f;
#pragma unroll
      for (int i = 0; i < 4; ++i) {
        int row = r0 + wr * 64 + mi * 16 + g4 * 4 + i;
        float v = acc[mi][ni][i] + bv;
        if (OUT_MODE == 1)
          ((ushort*)Cout)[(size_t)row * N + col] = f2b(v);
        else
          ((float*)Cout)[(size_t)row * N + col] = v;
      }
    }
  }
}

// ---------------- RoPE in-place on QKV (q heads 0..27, k heads 28..31) ----------------
__global__ void rope_kernel(ushort* __restrict__ QKV, const int* __restrict__ pos_ids) {
  int t = blockIdx.x;
  float pos = (float)pos_ids[t];
  ushort* row = QKV + (size_t)t * QKV_N;
  for (int p = threadIdx.x; p < 2048; p += 256) {  // 32 heads * 64 pairs
    int head = p >> 6;
    int d = p & 63;
    float inv = expf(-0.2158673524f * (float)d);  // theta^(-d/64), ln(1e6)/64
    float fr = pos * inv;
    float s, c;
    sincosf(fr, &s, &c);
    int c1 = head * 128 + d, c2 = c1 + 64;
    float x1 = b2f(row[c1]), x2 = b2f(row[c2]);
    row[c1] = f2b(x1 * c - x2 * s);
    row[c2] = f2b(x2 * c + x1 * s);
  }
}

// ---------------- build VT[kh][d][s] from QKV v-part ----------------
__global__ void build_vt_kernel(const ushort* __restrict__ QKV, ushort* __restrict__ VT) {
  __shared__ ushort tile[32][33];
  int kh = blockIdx.z;
  int d0 = blockIdx.x * 32, s0 = blockIdx.y * 32;
  int tx = threadIdx.x, ty = threadIdx.y;
#pragma unroll
  for (int j = 0; j < 4; ++j)
    tile[ty + j * 8][tx] =
        QKV[(size_t)(s0 + ty + j * 8) * QKV_N + (H_DIM + KV_N) + kh * 128 + d0 + tx];
  __syncthreads();
#pragma unroll
  for (int j = 0; j < 4; ++j)
    VT[((size_t)kh * 128 + d0 + ty + j * 8) * T_SEQ + s0 + tx] = tile[tx][ty + j * 8];
}

// ---------------- flash attention v2: 4 waves/block, 64 q-rows, KVB=64 ----------------
// LDS-staged K/V (double-buffered, XOR-swizzled, 2-phase pipeline), per-wave P tile.
__global__ __launch_bounds__(256) void attn_kernel(const ushort* __restrict__ QKV,
                                                   const ushort* __restrict__ VT,
                                                   ushort* __restrict__ O) {
  __shared__ ushort Ksm[2][64 * 128];   // [s-row][d], row=256B, swizzled
  __shared__ ushort Vsm[2][128 * 64];   // [d-row][s], row=128B, swizzled
  __shared__ ushort Psm[4][16 * 68];    // per-wave P tile, pitch 68
  const int tid = threadIdx.x;
  const int lane = tid & 63;
  const int w = tid >> 6;
  const int g4 = lane >> 4, l16 = lane & 15;
  const int qsb = (gridDim.x - 1) - blockIdx.x;  // heavy blocks dispatched first
  const int h = blockIdx.y;
  const int kh = h / 7;
  const int t0 = qsb * 64 + w * 16;  // this wave's first q row

  // Q fragments: lane holds Q[t0+l16][kk*32 + g4*8 + j]
  bf16x8 qf[4];
  {
    const ushort* qrow = QKV + (size_t)(t0 + l16) * QKV_N + h * 128;
#pragma unroll
    for (int kk = 0; kk < 4; ++kk) qf[kk] = *(const bf16x8*)(qrow + kk * 32 + g4 * 8);
  }

  f32x4 acc[8];
#pragma unroll
  for (int i = 0; i < 8; ++i) acc[i] = f32x4{0.f, 0.f, 0.f, 0.f};
  float m[4], lsum[4];
#pragma unroll
  for (int i = 0; i < 4; ++i) { m[i] = -3e38f; lsum[i] = 0.f; }

  const size_t kcol0 = (size_t)(H_DIM + kh * 128) * 2;  // byte offset of K slice in a QKV row
  const char* Vg = (const char*)VT + (size_t)kh * 128 * T_SEQ * 2;

  // stage K (64x128) and V (128x64) tiles for block s0 into buffer b
  auto stage = [&](int b, int s0) {
#pragma unroll
    for (int rnd = 0; rnd < 4; ++rnd) {
      int row = rnd * 16 + (tid >> 4);
      int colb = (tid & 15) * 16;
      int scolb = colb ^ ((row & 7) << 4);
      const char* src = (const char*)QKV + (size_t)(s0 + row) * (QKV_N * 2) + kcol0 + scolb;
      gload_lds16(src, (char*)Ksm[b] + rnd * 4096 + w * 1024);
    }
#pragma unroll
    for (int rnd = 0; rnd < 4; ++rnd) {
      int row = rnd * 32 + (tid >> 3);
      int colb = (tid & 7) * 16;
      int scolb = colb ^ ((row & 7) << 4);
      const char* src = Vg + (size_t)row * (T_SEQ * 2) + (size_t)s0 * 2 + scolb;
      gload_lds16(src, (char*)Vsm[b] + rnd * 4096 + w * 1024);
    }
  };

  stage(0, 0);
  const int nblk = qsb + 1;
  for (int sb = 0; sb < nblk; ++sb) {
    const int s0 = sb * 64;
    const int cur = sb & 1;
    __syncthreads();  // drains vmcnt: buf[cur] ready; all waves done with buf[cur^1]
    if (sb + 1 < nblk) stage(cur ^ 1, s0 + 64);  // overlap next-tile loads with compute

    // ---- S(16x64) = Q @ K^T ----
    f32x4 sacc[4];
#pragma unroll
    for (int c = 0; c < 4; ++c) sacc[c] = f32x4{0.f, 0.f, 0.f, 0.f};
#pragma unroll
    for (int c = 0; c < 4; ++c) {
      int krow = c * 16 + l16;
      int swz = (krow & 7) << 4;
#pragma unroll
      for (int kk = 0; kk < 4; ++kk) {
        bf16x8 kf = *(const bf16x8*)((const char*)Ksm[cur] + krow * 256 + ((kk * 64 + g4 * 16) ^ swz));
        sacc[c] = __builtin_amdgcn_mfma_f32_16x16x32_bf16(qf[kk], kf, sacc[c], 0, 0, 0);
      }
    }
    // ---- scale + causal + online softmax (row r = g4*4+i, col = c*16+l16) ----
#pragma unroll
    for (int i = 0; i < 4; ++i) {
      int t = t0 + g4 * 4 + i;
      float rmax = -3e38f;
#pragma unroll
      for (int c = 0; c < 4; ++c) {
        int s = s0 + c * 16 + l16;
        float v = sacc[c][i] * 0.08838834764831845f;
        v = (s <= t) ? v : -1e30f;
        sacc[c][i] = v;
        rmax = fmaxf(rmax, v);
      }
#pragma unroll
      for (int mk = 1; mk < 16; mk <<= 1) rmax = fmaxf(rmax, __shfl_xor(rmax, mk, 64));
      float mnew = fmaxf(m[i], rmax);
      float rescale = __expf(m[i] - mnew);
      m[i] = mnew;
      float ps = 0.f;
#pragma unroll
      for (int c = 0; c < 4; ++c) {
        float pv = __expf(sacc[c][i] - mnew);
        sacc[c][i] = pv;
        ps += pv;
      }
#pragma unroll
      for (int mk = 1; mk < 16; mk <<= 1) ps += __shfl_xor(ps, mk, 64);
      lsum[i] = lsum[i] * rescale + ps;
#pragma unroll
      for (int dc = 0; dc < 8; ++dc) acc[dc][i] *= rescale;
    }
    // ---- P -> per-wave LDS (D-layout), read back as A-frags ----
#pragma unroll
    for (int i = 0; i < 4; ++i)
#pragma unroll
      for (int c = 0; c < 4; ++c)
        Psm[w][(g4 * 4 + i) * 68 + c * 16 + l16] = f2b(sacc[c][i]);
    bf16x8 pf0 = *(const bf16x8*)(&Psm[w][l16 * 68 + g4 * 8]);
    bf16x8 pf1 = *(const bf16x8*)(&Psm[w][l16 * 68 + 32 + g4 * 8]);
    // ---- O += P @ V ----
#pragma unroll
    for (int dc = 0; dc < 8; ++dc) {
      int vrow = dc * 16 + l16;
      int swz = (vrow & 7) << 4;
      bf16x8 vf0 = *(const bf16x8*)((const char*)Vsm[cur] + vrow * 128 + ((g4 * 16) ^ swz));
      acc[dc] = __builtin_amdgcn_mfma_f32_16x16x32_bf16(pf0, vf0, acc[dc], 0, 0, 0);
      bf16x8 vf1 = *(const bf16x8*)((const char*)Vsm[cur] + vrow * 128 + ((64 + g4 * 16) ^ swz));
      acc[dc] = __builtin_amdgcn_mfma_f32_16x16x32_bf16(pf1, vf1, acc[dc], 0, 0, 0);
    }
  }
  // epilogue
#pragma unroll
  for (int i = 0; i < 4; ++i) {
    float inv = 1.f / lsum[i];
    int t = t0 + g4 * 4 + i;
#pragma unroll
    for (int dc = 0; dc < 8; ++dc)
      O[(size_t)t * H_DIM + h * 128 + dc * 16 + l16] = f2b(acc[dc][i] * inv);
  }
}

extern "C" void kernel_launch(void* const* d_in, const int* in_sizes, int n_in,
                              void* d_out, int out_size, void* d_ws, size_t ws_size,
                              hipStream_t stream) {
  const float* hs = (const float*)d_in[0];
  const int* pos = (const int*)d_in[1];
  const float* Wq = (const float*)d_in[2];
  const float* bq = (const float*)d_in[3];
  const float* Wk = (const float*)d_in[4];
  const float* bk = (const float*)d_in[5];
  const float* Wv = (const float*)d_in[6];
  const float* bv = (const float*)d_in[7];
  const float* Wo = (const float*)d_in[8];
  float* out = (float*)d_out;

  char* p = (char*)d_ws;
  ushort* hs_b = (ushort*)p;  p += (size_t)T_SEQ * H_DIM * 2;
  ushort* WqkvT = (ushort*)p; p += (size_t)QKV_N * H_DIM * 2;
  ushort* WoT = (ushort*)p;   p += (size_t)H_DIM * H_DIM * 2;
  float* biasb = (float*)p;   p += (size_t)QKV_N * 4;
  ushort* QKV = (ushort*)p;   p += (size_t)T_SEQ * QKV_N * 2;
  ushort* VT = (ushort*)p;    p += (size_t)NKVH * HD * T_SEQ * 2;
  ushort* Obuf = (ushort*)p;  p += (size_t)T_SEQ * H_DIM * 2;

  cast_bf16_kernel<<<T_SEQ * H_DIM / 1024, 256, 0, stream>>>(hs, hs_b);
  transpose_cast_kernel<<<dim3(H_DIM / 32, H_DIM / 32), dim3(32, 8), 0, stream>>>(Wq, WqkvT, H_DIM, H_DIM);
  transpose_cast_kernel<<<dim3(KV_N / 32, H_DIM / 32), dim3(32, 8), 0, stream>>>(
      Wk, WqkvT + (size_t)H_DIM * H_DIM, H_DIM, KV_N);
  transpose_cast_kernel<<<dim3(KV_N / 32, H_DIM / 32), dim3(32, 8), 0, stream>>>(
      Wv, WqkvT + (size_t)(H_DIM + KV_N) * H_DIM, H_DIM, KV_N);
  transpose_cast_kernel<<<dim3(H_DIM / 32, H_DIM / 32), dim3(32, 8), 0, stream>>>(Wo, WoT, H_DIM, H_DIM);
  concat_bias_kernel<<<QKV_N / 256, 256, 0, stream>>>(bq, bk, bv, biasb);
  gemm_bt_kernel<1><<<dim3(QKV_N / 128, T_SEQ / 128), 256, 0, stream>>>(
      hs_b, WqkvT, biasb, QKV, T_SEQ, QKV_N, K_DIM);
  rope_kernel<<<T_SEQ, 256, 0, stream>>>(QKV, pos);
  build_vt_kernel<<<dim3(HD / 32, T_SEQ / 32, NKVH), dim3(32, 8), 0, stream>>>(QKV, VT);
  attn_kernel<<<dim3(T_SEQ / 64, NQH), 256, 0, stream>>>(QKV, VT, Obuf);
  gemm_bt_kernel<0><<<dim3(H_DIM / 128, T_SEQ / 128), 256, 0, stream>>>(
      Obuf, WoT, nullptr, out, T_SEQ, H_DIM, K_DIM);
}

// Round 3
// 366.989 us; speedup vs baseline: 1.7098x; 1.2413x over previous
//
#include <hip/hip_runtime.h>
#include <hip/hip_bf16.h>
#include <stdint.h>

#define T_SEQ 2048
#define H_DIM 3584
#define NQH 28
#define NKVH 4
#define HD 128
#define KV_N 512          // NKVH*HD
#define QKV_N 4608        // 3584 + 512 + 512
#define K_DIM 3584

typedef __bf16 bf16x8 __attribute__((ext_vector_type(8)));
typedef float f32x4 __attribute__((ext_vector_type(4)));
typedef float f32x16 __attribute__((ext_vector_type(16)));
typedef uint u32x4 __attribute__((ext_vector_type(4)));

#if __has_builtin(__builtin_amdgcn_exp2f)
#define EXP2 __builtin_amdgcn_exp2f
#else
#define EXP2 exp2f
#endif

__device__ __forceinline__ ushort f2b(float f) {
  uint x = __builtin_bit_cast(uint, f);
  x += 0x7fffu + ((x >> 16) & 1u);
  return (ushort)(x >> 16);
}
__device__ __forceinline__ float b2f(ushort u) {
  return __builtin_bit_cast(float, (uint)u << 16);
}

__device__ __forceinline__ void gload_lds16(const void* gptr, void* ldsptr) {
  __builtin_amdgcn_global_load_lds(
      (const __attribute__((address_space(1))) uint32_t*)gptr,
      (__attribute__((address_space(3))) uint32_t*)ldsptr, 16, 0, 0);
}

// pack two f32 -> one u32 of 2 bf16 (lo = a, hi = b)
__device__ __forceinline__ uint cvtpk(float a, float b) {
  uint r;
  asm("v_cvt_pk_bf16_f32 %0, %1, %2" : "=v"(r) : "v"(a), "v"(b));
  return r;
}
// swap a.hi-lanes with b.lo-lanes: a'[0:31]=a[0:31], a'[32:63]=b[0:31],
//                                  b'[0:31]=a[32:63], b'[32:63]=b[32:63]
__device__ __forceinline__ void swap32(uint& a, uint& b) {
#if __has_builtin(__builtin_amdgcn_permlane32_swap)
  typedef int i32x2 __attribute__((ext_vector_type(2)));
  i32x2 r = __builtin_amdgcn_permlane32_swap((int)a, (int)b, false, false);
  a = (uint)r.x; b = (uint)r.y;
#else
  int lo = ((threadIdx.x & 63) < 32);
  uint sa = __shfl_xor((int)a, 32, 64);
  uint sb = __shfl_xor((int)b, 32, 64);
  uint na = lo ? a : sb;
  uint nb = lo ? sa : b;
  a = na; b = nb;
#endif
}

// ---------------- cast hidden fp32 -> bf16 ----------------
__global__ void cast_bf16_kernel(const float* __restrict__ in, ushort* __restrict__ out) {
  int i = (blockIdx.x * 256 + threadIdx.x) * 4;
  float4 v = *(const float4*)(in + i);
  ushort4 o = make_ushort4(f2b(v.x), f2b(v.y), f2b(v.z), f2b(v.w));
  *(ushort4*)(out + i) = o;
}

// ---------------- transpose + cast: W (K x N) fp32 -> WT (N x K) bf16 ----------------
__global__ void transpose_cast_kernel(const float* __restrict__ W, ushort* __restrict__ WT,
                                      int K, int N) {
  __shared__ float tile[32][33];
  int n0 = blockIdx.x * 32, k0 = blockIdx.y * 32;
  int tx = threadIdx.x, ty = threadIdx.y;  // 32 x 8
#pragma unroll
  for (int j = 0; j < 4; ++j)
    tile[ty + j * 8][tx] = W[(size_t)(k0 + ty + j * 8) * N + n0 + tx];
  __syncthreads();
#pragma unroll
  for (int j = 0; j < 4; ++j)
    WT[(size_t)(n0 + ty + j * 8) * K + k0 + tx] = f2b(tile[tx][ty + j * 8]);
}

// ---------------- bias concat [bq | bk | bv] ----------------
__global__ void concat_bias_kernel(const float* __restrict__ bq, const float* __restrict__ bk,
                                   const float* __restrict__ bv, float* __restrict__ out) {
  int i = blockIdx.x * 256 + threadIdx.x;
  float v;
  if (i < H_DIM) v = bq[i];
  else if (i < H_DIM + KV_N) v = bk[i - H_DIM];
  else v = bv[i - H_DIM - KV_N];
  out[i] = v;
}

// ---------------- m97-style GEMM: C = A(MxK) @ B(KxN), BT given as (N x K) bf16 ----------------
template <int OUT_MODE>
__global__ __launch_bounds__(256) void gemm_bt_kernel(
    const ushort* __restrict__ A, const ushort* __restrict__ BT,
    const float* __restrict__ bias, void* __restrict__ Cout, int M, int N, int K) {
  __shared__ ushort As[128 * 64];
  __shared__ ushort Bs[128 * 64];
  const int tid = threadIdx.x;
  const int lane = tid & 63;
  const int w = tid >> 6;
  const int wr = w >> 1, wc = w & 1;
  const int g4 = lane >> 4, l16 = lane & 15;
  const int r0 = blockIdx.y * 128, c0 = blockIdx.x * 128;
  const size_t rowbytes = (size_t)K * 2;

  f32x4 acc[4][4];
#pragma unroll
  for (int a = 0; a < 4; ++a)
#pragma unroll
    for (int b = 0; b < 4; ++b) acc[a][b] = f32x4{0.f, 0.f, 0.f, 0.f};

  for (int kt = 0; kt < K; kt += 64) {
#pragma unroll
    for (int j = 0; j < 4; ++j) {
      int b = (j * 256 + tid) * 16;  // byte index in 16KB tile
      int r = b >> 7;                // row (64 bf16 = 128B per row)
      int cb = b & 127;              // byte within row
      const char* ga = (const char*)A + (size_t)(r0 + r) * rowbytes + (size_t)kt * 2 + cb;
      gload_lds16(ga, (char*)As + j * 4096 + w * 1024);
      const char* gb = (const char*)BT + (size_t)(c0 + r) * rowbytes + (size_t)kt * 2 + cb;
      gload_lds16(gb, (char*)Bs + j * 4096 + w * 1024);
    }
    __syncthreads();
#pragma unroll
    for (int kk = 0; kk < 2; ++kk) {
      bf16x8 af[4], bfr[4];
#pragma unroll
      for (int mi = 0; mi < 4; ++mi) {
        int row = wr * 64 + mi * 16 + l16;
        af[mi] = *(const bf16x8*)((const char*)As + row * 128 + kk * 64 + g4 * 16);
      }
#pragma unroll
      for (int ni = 0; ni < 4; ++ni) {
        int row = wc * 64 + ni * 16 + l16;
        bfr[ni] = *(const bf16x8*)((const char*)Bs + row * 128 + kk * 64 + g4 * 16);
      }
#pragma unroll
      for (int mi = 0; mi < 4; ++mi)
#pragma unroll
        for (int ni = 0; ni < 4; ++ni)
          acc[mi][ni] = __builtin_amdgcn_mfma_f32_16x16x32_bf16(af[mi], bfr[ni], acc[mi][ni], 0, 0, 0);
    }
    __syncthreads();
  }
#pragma unroll
  for (int mi = 0; mi < 4; ++mi) {
#pragma unroll
    for (int ni = 0; ni < 4; ++ni) {
      int col = c0 + wc * 64 + ni * 16 + l16;
      float bv = (OUT_MODE == 1) ? bias[col] : 0.f;
#pragma unroll
      for (int i = 0; i < 4; ++i) {
        int row = r0 + wr * 64 + mi * 16 + g4 * 4 + i;
        float v = acc[mi][ni][i] + bv;
        if (OUT_MODE == 1)
          ((ushort*)Cout)[(size_t)row * N + col] = f2b(v);
        else
          ((float*)Cout)[(size_t)row * N + col] = v;
      }
    }
  }
}

// ---------------- RoPE in-place on QKV (q heads 0..27, k heads 28..31) ----------------
__global__ void rope_kernel(ushort* __restrict__ QKV, const int* __restrict__ pos_ids) {
  int t = blockIdx.x;
  float pos = (float)pos_ids[t];
  ushort* row = QKV + (size_t)t * QKV_N;
  for (int p = threadIdx.x; p < 2048; p += 256) {  // 32 heads * 64 pairs
    int head = p >> 6;
    int d = p & 63;
    float inv = expf(-0.2158673524f * (float)d);  // theta^(-d/64), ln(1e6)/64
    float fr = pos * inv;
    float s, c;
    sincosf(fr, &s, &c);
    int c1 = head * 128 + d, c2 = c1 + 64;
    float x1 = b2f(row[c1]), x2 = b2f(row[c2]);
    row[c1] = f2b(x1 * c - x2 * s);
    row[c2] = f2b(x2 * c + x1 * s);
  }
}

// ---------------- build VT[kh][d][s] from QKV v-part ----------------
__global__ void build_vt_kernel(const ushort* __restrict__ QKV, ushort* __restrict__ VT) {
  __shared__ ushort tile[32][33];
  int kh = blockIdx.z;
  int d0 = blockIdx.x * 32, s0 = blockIdx.y * 32;
  int tx = threadIdx.x, ty = threadIdx.y;
#pragma unroll
  for (int j = 0; j < 4; ++j)
    tile[ty + j * 8][tx] =
        QKV[(size_t)(s0 + ty + j * 8) * QKV_N + (H_DIM + KV_N) + kh * 128 + d0 + tx];
  __syncthreads();
#pragma unroll
  for (int j = 0; j < 4; ++j)
    VT[((size_t)kh * 128 + d0 + ty + j * 8) * T_SEQ + s0 + tx] = tile[tx][ty + j * 8];
}

// ---------------- flash attention v3: swapped-QK^T, in-register softmax ----------------
// 4 waves/block; waves 0-1: heavy 64-row chunk (31-p), waves 2-3: light chunk p.
// Per wave: 32 q-rows (q = lane&31), KVBLK=64, K LDS-staged (XOR-swz), V direct from L2.
__global__ __launch_bounds__(256, 2) void attn_kernel(const ushort* __restrict__ QKV,
                                                      const ushort* __restrict__ VT,
                                                      ushort* __restrict__ O) {
  __shared__ __align__(16) char Ksm[2][16384];  // 64 s-rows x 256B (128 d bf16), swizzled
  const int tid = threadIdx.x;
  const int lane = tid & 63;
  const int w = tid >> 6;
  const int q = lane & 31;       // q-row / kpos-local / d-local lane field
  const int h = lane >> 5;       // half selector
  const int p = blockIdx.x;      // pair index 0..15
  const int hq = blockIdx.y;     // q-head
  const int kh = hq / 7;
  const int t0w = (w < 2) ? ((31 - p) * 64 + w * 32) : (p * 64 + (w - 2) * 32);
  const int myN = (t0w >> 6) + 1;   // KV tiles this wave needs
  const int nIt = 32 - p;           // block-level iterations (heavy wave's count)

  // Q B-frags, pre-scaled by (1/sqrt(128))*log2(e): lane holds Q[q][cc*16 + h*8 + j]
  const float qs = 0.12751744f;
  bf16x8 qf[8];
  {
    const ushort* qrow = QKV + (size_t)(t0w + q) * QKV_N + hq * 128;
#pragma unroll
    for (int cc = 0; cc < 8; ++cc) {
      bf16x8 v = *(const bf16x8*)(qrow + cc * 16 + h * 8);
#pragma unroll
      for (int j = 0; j < 8; ++j) v[j] = (__bf16)((float)v[j] * qs);
      qf[cc] = v;
    }
  }

  f32x16 acc[4];
#pragma unroll
  for (int db = 0; db < 4; ++db) acc[db] = f32x16{};
  float m = -3e38f, lsum = 0.f;

  const size_t kbyte0 = (size_t)(H_DIM + kh * 128) * 2;
  const ushort* VTh = VT + (size_t)kh * 128 * T_SEQ;

  auto stage = [&](int buf, int s0) {
#pragma unroll
    for (int rnd = 0; rnd < 4; ++rnd) {
      int d = rnd * 4096 + tid * 16;  // dest byte in 16KB tile
      int r = d >> 8;                 // s-row
      int cb = d & 255;               // byte within row
      const char* src = (const char*)QKV + (size_t)(s0 + r) * (QKV_N * 2) + kbyte0 +
                        (cb ^ ((r & 15) << 4));
      gload_lds16(src, (char*)Ksm[buf] + rnd * 4096 + w * 1024);
    }
  };

  stage(0, 0);
  for (int sb = 0; sb < nIt; ++sb) {
    __syncthreads();  // buf[sb&1] ready; everyone done with buf[(sb+1)&1]
    if (sb + 1 < nIt) stage((sb + 1) & 1, (sb + 1) * 64);
    if (sb >= myN) continue;  // light waves idle (still stage + barrier)

    // ---- V A-frags direct from L2 (independent: issue early) ----
    bf16x8 vf[4][4];
#pragma unroll
    for (int db = 0; db < 4; ++db)
#pragma unroll
      for (int c = 0; c < 4; ++c)
        vf[db][c] = *(const bf16x8*)(VTh + (size_t)(db * 32 + q) * T_SEQ + sb * 64 + c * 16 + h * 8);

    // ---- S^T(64 kpos x 32 q) = K @ Q^T : two 32x32 subtiles ----
    const char* Kb = Ksm[sb & 1];
    const int swz = (q & 15) << 4;
    f32x16 sa0 = {}, sa1 = {};
#pragma unroll
    for (int cc = 0; cc < 8; ++cc) {
      int colb = (cc * 32 + h * 16) ^ swz;
      bf16x8 kf0 = *(const bf16x8*)(Kb + q * 256 + colb);
      bf16x8 kf1 = *(const bf16x8*)(Kb + (32 + q) * 256 + colb);
      sa0 = __builtin_amdgcn_mfma_f32_32x32x16_bf16(kf0, qf[cc], sa0, 0, 0, 0);
      sa1 = __builtin_amdgcn_mfma_f32_32x32x16_bf16(kf1, qf[cc], sa1, 0, 0, 0);
    }

    // ---- causal mask (only on this wave's last tile) ----
    if (sb == myN - 1) {
      const int t = t0w + q;
#pragma unroll
      for (int r = 0; r < 16; ++r) {
        int kl = (r & 3) + 8 * (r >> 2) + 4 * h;
        if (sb * 64 + kl > t) sa0[r] = -1e30f;
        if (sb * 64 + 32 + kl > t) sa1[r] = -1e30f;
      }
    }

    // ---- in-lane softmax (log2 units), defer-max THR=8 ----
    float pmax = -3e38f;
#pragma unroll
    for (int r = 0; r < 16; ++r) pmax = fmaxf(pmax, fmaxf(sa0[r], sa1[r]));
    pmax = fmaxf(pmax, __shfl_xor(pmax, 32, 64));
    if (__any(pmax > m + 8.f)) {
      float mn = fmaxf(m, pmax);
      float rs = EXP2(m - mn);
      m = mn;
      lsum *= rs;
#pragma unroll
      for (int db = 0; db < 4; ++db)
#pragma unroll
        for (int r = 0; r < 16; ++r) acc[db][r] *= rs;
    }
    float psum = 0.f;
#pragma unroll
    for (int r = 0; r < 16; ++r) { sa0[r] = EXP2(sa0[r] - m); psum += sa0[r]; }
#pragma unroll
    for (int r = 0; r < 16; ++r) { sa1[r] = EXP2(sa1[r] - m); psum += sa1[r]; }
    lsum += psum;  // per-half partial; combined at epilogue

    // ---- P -> bf16 B-frags (cvt_pk + permlane32_swap), PV: acc = V^T @ P^T ----
#pragma unroll
    for (int c = 0; c < 4; ++c) {
      const f32x16& P = (c < 2) ? sa0 : sa1;
      const int e = c & 1;
      uint a0 = cvtpk(P[8 * e + 0], P[8 * e + 1]);
      uint a1 = cvtpk(P[8 * e + 2], P[8 * e + 3]);
      uint a2 = cvtpk(P[8 * e + 4], P[8 * e + 5]);
      uint a3 = cvtpk(P[8 * e + 6], P[8 * e + 7]);
      swap32(a0, a2);  // a0 = w0, a2 = w2
      swap32(a1, a3);  // a1 = w1, a3 = w3
      u32x4 pw = {a0, a1, a2, a3};
      bf16x8 pf = __builtin_bit_cast(bf16x8, pw);
#pragma unroll
      for (int db = 0; db < 4; ++db)
        acc[db] = __builtin_amdgcn_mfma_f32_32x32x16_bf16(vf[db][c], pf, acc[db], 0, 0, 0);
    }
  }

  // ---- epilogue: combine lsum halves, normalize, store ----
  float lt = lsum + __shfl_xor(lsum, 32, 64);
  float inv = 1.f / lt;
  ushort* orow = O + (size_t)(t0w + q) * H_DIM + hq * 128;
#pragma unroll
  for (int db = 0; db < 4; ++db) {
#pragma unroll
    for (int rg = 0; rg < 4; ++rg) {
      ushort4 o;
      o.x = f2b(acc[db][rg * 4 + 0] * inv);
      o.y = f2b(acc[db][rg * 4 + 1] * inv);
      o.z = f2b(acc[db][rg * 4 + 2] * inv);
      o.w = f2b(acc[db][rg * 4 + 3] * inv);
      *(ushort4*)(orow + db * 32 + rg * 8 + h * 4) = o;
    }
  }
}

extern "C" void kernel_launch(void* const* d_in, const int* in_sizes, int n_in,
                              void* d_out, int out_size, void* d_ws, size_t ws_size,
                              hipStream_t stream) {
  const float* hs = (const float*)d_in[0];
  const int* pos = (const int*)d_in[1];
  const float* Wq = (const float*)d_in[2];
  const float* bq = (const float*)d_in[3];
  const float* Wk = (const float*)d_in[4];
  const float* bk = (const float*)d_in[5];
  const float* Wv = (const float*)d_in[6];
  const float* bv = (const float*)d_in[7];
  const float* Wo = (const float*)d_in[8];
  float* out = (float*)d_out;

  char* p = (char*)d_ws;
  ushort* hs_b = (ushort*)p;  p += (size_t)T_SEQ * H_DIM * 2;
  ushort* WqkvT = (ushort*)p; p += (size_t)QKV_N * H_DIM * 2;
  ushort* WoT = (ushort*)p;   p += (size_t)H_DIM * H_DIM * 2;
  float* biasb = (float*)p;   p += (size_t)QKV_N * 4;
  ushort* QKV = (ushort*)p;   p += (size_t)T_SEQ * QKV_N * 2;
  ushort* VT = (ushort*)p;    p += (size_t)NKVH * HD * T_SEQ * 2;
  ushort* Obuf = (ushort*)p;  p += (size_t)T_SEQ * H_DIM * 2;

  cast_bf16_kernel<<<T_SEQ * H_DIM / 1024, 256, 0, stream>>>(hs, hs_b);
  transpose_cast_kernel<<<dim3(H_DIM / 32, H_DIM / 32), dim3(32, 8), 0, stream>>>(Wq, WqkvT, H_DIM, H_DIM);
  transpose_cast_kernel<<<dim3(KV_N / 32, H_DIM / 32), dim3(32, 8), 0, stream>>>(
      Wk, WqkvT + (size_t)H_DIM * H_DIM, H_DIM, KV_N);
  transpose_cast_kernel<<<dim3(KV_N / 32, H_DIM / 32), dim3(32, 8), 0, stream>>>(
      Wv, WqkvT + (size_t)(H_DIM + KV_N) * H_DIM, H_DIM, KV_N);
  transpose_cast_kernel<<<dim3(H_DIM / 32, H_DIM / 32), dim3(32, 8), 0, stream>>>(Wo, WoT, H_DIM, H_DIM);
  concat_bias_kernel<<<QKV_N / 256, 256, 0, stream>>>(bq, bk, bv, biasb);
  gemm_bt_kernel<1><<<dim3(QKV_N / 128, T_SEQ / 128), 256, 0, stream>>>(
      hs_b, WqkvT, biasb, QKV, T_SEQ, QKV_N, K_DIM);
  rope_kernel<<<T_SEQ, 256, 0, stream>>>(QKV, pos);
  build_vt_kernel<<<dim3(HD / 32, T_SEQ / 32, NKVH), dim3(32, 8), 0, stream>>>(QKV, VT);
  attn_kernel<<<dim3(16, NQH), 256, 0, stream>>>(QKV, VT, Obuf);
  gemm_bt_kernel<0><<<dim3(H_DIM / 128, T_SEQ / 128), 256, 0, stream>>>(
      Obuf, WoT, nullptr, out, T_SEQ, H_DIM, K_DIM);
}

// Round 4
// 366.593 us; speedup vs baseline: 1.7116x; 1.0011x over previous
//
#include <hip/hip_runtime.h>
#include <hip/hip_bf16.h>
#include <stdint.h>

#define T_SEQ 2048
#define H_DIM 3584
#define NQH 28
#define NKVH 4
#define HD 128
#define KV_N 512          // NKVH*HD
#define QKV_N 4608        // 3584 + 512 + 512
#define K_DIM 3584

typedef __bf16 bf16x8 __attribute__((ext_vector_type(8)));
typedef float f32x4 __attribute__((ext_vector_type(4)));
typedef float f32x16 __attribute__((ext_vector_type(16)));
typedef uint u32x4 __attribute__((ext_vector_type(4)));

#if __has_builtin(__builtin_amdgcn_exp2f)
#define EXP2 __builtin_amdgcn_exp2f
#else
#define EXP2 exp2f
#endif

__device__ __forceinline__ ushort f2b(float f) {
  uint x = __builtin_bit_cast(uint, f);
  x += 0x7fffu + ((x >> 16) & 1u);
  return (ushort)(x >> 16);
}
__device__ __forceinline__ float b2f(ushort u) {
  return __builtin_bit_cast(float, (uint)u << 16);
}

__device__ __forceinline__ void gload_lds16(const void* gptr, void* ldsptr) {
  __builtin_amdgcn_global_load_lds(
      (const __attribute__((address_space(1))) uint32_t*)gptr,
      (__attribute__((address_space(3))) uint32_t*)ldsptr, 16, 0, 0);
}

#define FULL_BARRIER()                              \
  do {                                              \
    asm volatile("" ::: "memory");                  \
    __builtin_amdgcn_s_barrier();                   \
    asm volatile("" ::: "memory");                  \
  } while (0)

// pack two f32 -> one u32 of 2 bf16 (lo = a, hi = b)
__device__ __forceinline__ uint cvtpk(float a, float b) {
  uint r;
  asm("v_cvt_pk_bf16_f32 %0, %1, %2" : "=v"(r) : "v"(a), "v"(b));
  return r;
}
__device__ __forceinline__ void swap32(uint& a, uint& b) {
#if __has_builtin(__builtin_amdgcn_permlane32_swap)
  typedef int i32x2 __attribute__((ext_vector_type(2)));
  i32x2 r = __builtin_amdgcn_permlane32_swap((int)a, (int)b, false, false);
  a = (uint)r.x; b = (uint)r.y;
#else
  int lo = ((threadIdx.x & 63) < 32);
  uint sa = __shfl_xor((int)a, 32, 64);
  uint sb = __shfl_xor((int)b, 32, 64);
  uint na = lo ? a : sb;
  uint nb = lo ? sa : b;
  a = na; b = nb;
#endif
}

// ---------------- cast hidden fp32 -> bf16 ----------------
__global__ void cast_bf16_kernel(const float* __restrict__ in, ushort* __restrict__ out) {
  int i = (blockIdx.x * 256 + threadIdx.x) * 4;
  float4 v = *(const float4*)(in + i);
  ushort4 o = make_ushort4(f2b(v.x), f2b(v.y), f2b(v.z), f2b(v.w));
  *(ushort4*)(out + i) = o;
}

// ---------------- transpose + cast: W (K x N) fp32 -> WT (N x K) bf16 ----------------
__global__ void transpose_cast_kernel(const float* __restrict__ W, ushort* __restrict__ WT,
                                      int K, int N) {
  __shared__ float tile[32][33];
  int n0 = blockIdx.x * 32, k0 = blockIdx.y * 32;
  int tx = threadIdx.x, ty = threadIdx.y;  // 32 x 8
#pragma unroll
  for (int j = 0; j < 4; ++j)
    tile[ty + j * 8][tx] = W[(size_t)(k0 + ty + j * 8) * N + n0 + tx];
  __syncthreads();
#pragma unroll
  for (int j = 0; j < 4; ++j)
    WT[(size_t)(n0 + ty + j * 8) * K + k0 + tx] = f2b(tile[tx][ty + j * 8]);
}

// ---------------- bias concat [bq | bk | bv] ----------------
__global__ void concat_bias_kernel(const float* __restrict__ bq, const float* __restrict__ bk,
                                   const float* __restrict__ bv, float* __restrict__ out) {
  int i = blockIdx.x * 256 + threadIdx.x;
  float v;
  if (i < H_DIM) v = bq[i];
  else if (i < H_DIM + KV_N) v = bk[i - H_DIM];
  else v = bv[i - H_DIM - KV_N];
  out[i] = v;
}

// ---------------- 256x256-tile phase-pipelined GEMM (T3+T4+T5) ----------------
// C = A(MxK) @ B(KxN), BT given as (N x K) bf16. 8 waves (2Mx4N), BK=32,
// 3 LDS slots, counted vmcnt(4) at group boundary (never drains to 0 mid-loop).
template <int OUT_MODE>
__global__ __launch_bounds__(512, 2) void gemm256_kernel(
    const ushort* __restrict__ A, const ushort* __restrict__ BT,
    const float* __restrict__ bias, void* __restrict__ Cout, int M, int N, int K) {
  __shared__ __align__(16) ushort As[3][256 * 32];  // 3 x 16KB
  __shared__ __align__(16) ushort Bs[3][256 * 32];  // 3 x 16KB
  const int tid = threadIdx.x;
  const int lane = tid & 63;
  const int w = tid >> 6;            // 0..7
  const int wr = w >> 2, wc = w & 3; // 2 x 4 wave grid; per-wave out = 128x64
  const int g4 = lane >> 4, l16 = lane & 15;
  const int r0 = blockIdx.y * 256, c0 = blockIdx.x * 256;
  const int nk = K >> 5;  // number of 32-deep K-tiles

  f32x4 acc[8][4];
#pragma unroll
  for (int a = 0; a < 8; ++a)
#pragma unroll
    for (int b = 0; b < 4; ++b) acc[a][b] = f32x4{0.f, 0.f, 0.f, 0.f};

  // stage A-half of K-tile t into slot s: 2 gload_lds per thread
  auto stageA = [&](int s, int t) {
#pragma unroll
    for (int j = 0; j < 2; ++j) {
      int g = (j * 8 + w) * 64 + lane;  // granule 0..1023
      const ushort* src = A + (size_t)(r0 + (g >> 2)) * K + t * 32 + (g & 3) * 8;
      gload_lds16(src, (char*)As[s] + (j * 8 + w) * 1024);
    }
  };
  auto stageB = [&](int s, int t) {
#pragma unroll
    for (int j = 0; j < 2; ++j) {
      int g = (j * 8 + w) * 64 + lane;
      const ushort* src = BT + (size_t)(c0 + (g >> 2)) * K + t * 32 + (g & 3) * 8;
      gload_lds16(src, (char*)Bs[s] + (j * 8 + w) * 1024);
    }
  };

  // prologue: tiles 0 and 1; wait until tile 0 landed (4 loads of tile 1 in flight)
  stageA(0, 0); stageB(0, 0);
  stageA(1, 1); stageB(1, 1);
  asm volatile("s_waitcnt vmcnt(4)" ::: "memory");
  FULL_BARRIER();

  for (int t = 0; t < nk; ++t) {
    const int s = t % 3;
    const ushort* Asl = As[s];
    const ushort* Bsl = Bs[s];
    const bool pf = (t + 2 < nk);

    // ---- phase 0: ds_read A(mi 0-3) + B(ni 0-3), stage A of t+2, MFMA quadrant ----
    bf16x8 a0[4], b0[4];
#pragma unroll
    for (int mi = 0; mi < 4; ++mi)
      a0[mi] = *(const bf16x8*)(Asl + (wr * 128 + mi * 16 + l16) * 32 + g4 * 8);
#pragma unroll
    for (int ni = 0; ni < 4; ++ni)
      b0[ni] = *(const bf16x8*)(Bsl + (wc * 64 + ni * 16 + l16) * 32 + g4 * 8);
    if (pf) stageA((t + 2) % 3, t + 2);
    __builtin_amdgcn_sched_barrier(0);
    FULL_BARRIER();
    asm volatile("s_waitcnt lgkmcnt(0)" ::: "memory");
    __builtin_amdgcn_sched_barrier(0);
    __builtin_amdgcn_s_setprio(1);
#pragma unroll
    for (int mi = 0; mi < 4; ++mi)
#pragma unroll
      for (int ni = 0; ni < 4; ++ni)
        acc[mi][ni] = __builtin_amdgcn_mfma_f32_16x16x32_bf16(a0[mi], b0[ni], acc[mi][ni], 0, 0, 0);
    __builtin_amdgcn_s_setprio(0);
    __builtin_amdgcn_sched_barrier(0);
    FULL_BARRIER();

    // ---- phase 1: ds_read A(mi 4-7), stage B of t+2, MFMA quadrant ----
    bf16x8 a1[4];
#pragma unroll
    for (int mi = 0; mi < 4; ++mi)
      a1[mi] = *(const bf16x8*)(Asl + (wr * 128 + (mi + 4) * 16 + l16) * 32 + g4 * 8);
    if (pf) stageB((t + 2) % 3, t + 2);
    __builtin_amdgcn_sched_barrier(0);
    FULL_BARRIER();
    asm volatile("s_waitcnt lgkmcnt(0)" ::: "memory");
    __builtin_amdgcn_sched_barrier(0);
    __builtin_amdgcn_s_setprio(1);
#pragma unroll
    for (int mi = 0; mi < 4; ++mi)
#pragma unroll
      for (int ni = 0; ni < 4; ++ni)
        acc[mi + 4][ni] = __builtin_amdgcn_mfma_f32_16x16x32_bf16(a1[mi], b0[ni], acc[mi + 4][ni], 0, 0, 0);
    __builtin_amdgcn_s_setprio(0);
    __builtin_amdgcn_sched_barrier(0);
    // group boundary: ensure tile t+1 fully landed; keep tile t+2's 4 loads in flight
    if (t + 1 < nk) {
      if (pf) asm volatile("s_waitcnt vmcnt(4)" ::: "memory");
      else    asm volatile("s_waitcnt vmcnt(0)" ::: "memory");
    }
    FULL_BARRIER();
  }

  // epilogue: D row=(lane>>4)*4+i (within 16-row frag), col=lane&15
#pragma unroll
  for (int mi = 0; mi < 8; ++mi) {
#pragma unroll
    for (int ni = 0; ni < 4; ++ni) {
      int col = c0 + wc * 64 + ni * 16 + l16;
      float bv = (OUT_MODE == 1) ? bias[col] : 0.f;
#pragma unroll
      for (int i = 0; i < 4; ++i) {
        int row = r0 + wr * 128 + mi * 16 + g4 * 4 + i;
        float v = acc[mi][ni][i] + bv;
        if (OUT_MODE == 1)
          ((ushort*)Cout)[(size_t)row * N + col] = f2b(v);
        else
          ((float*)Cout)[(size_t)row * N + col] = v;
      }
    }
  }
}

// ---------------- RoPE in-place on QKV (q heads 0..27, k heads 28..31) ----------------
__global__ void rope_kernel(ushort* __restrict__ QKV, const int* __restrict__ pos_ids) {
  int t = blockIdx.x;
  float pos = (float)pos_ids[t];
  ushort* row = QKV + (size_t)t * QKV_N;
  for (int p = threadIdx.x; p < 2048; p += 256) {  // 32 heads * 64 pairs
    int head = p >> 6;
    int d = p & 63;
    float inv = expf(-0.2158673524f * (float)d);  // theta^(-d/64), ln(1e6)/64
    float fr = pos * inv;
    float s, c;
    sincosf(fr, &s, &c);
    int c1 = head * 128 + d, c2 = c1 + 64;
    float x1 = b2f(row[c1]), x2 = b2f(row[c2]);
    row[c1] = f2b(x1 * c - x2 * s);
    row[c2] = f2b(x2 * c + x1 * s);
  }
}

// ---------------- build VT[kh][d][s] from QKV v-part ----------------
__global__ void build_vt_kernel(const ushort* __restrict__ QKV, ushort* __restrict__ VT) {
  __shared__ ushort tile[32][33];
  int kh = blockIdx.z;
  int d0 = blockIdx.x * 32, s0 = blockIdx.y * 32;
  int tx = threadIdx.x, ty = threadIdx.y;
#pragma unroll
  for (int j = 0; j < 4; ++j)
    tile[ty + j * 8][tx] =
        QKV[(size_t)(s0 + ty + j * 8) * QKV_N + (H_DIM + KV_N) + kh * 128 + d0 + tx];
  __syncthreads();
#pragma unroll
  for (int j = 0; j < 4; ++j)
    VT[((size_t)kh * 128 + d0 + ty + j * 8) * T_SEQ + s0 + tx] = tile[tx][ty + j * 8];
}

// ---------------- flash attention v3: swapped-QK^T, in-register softmax ----------------
__global__ __launch_bounds__(256, 2) void attn_kernel(const ushort* __restrict__ QKV,
                                                      const ushort* __restrict__ VT,
                                                      ushort* __restrict__ O) {
  __shared__ __align__(16) char Ksm[2][16384];  // 64 s-rows x 256B (128 d bf16), swizzled
  const int tid = threadIdx.x;
  const int lane = tid & 63;
  const int w = tid >> 6;
  const int q = lane & 31;       // q-row / kpos-local / d-local lane field
  const int h = lane >> 5;       // half selector
  const int p = blockIdx.x;      // pair index 0..15
  const int hq = blockIdx.y;     // q-head
  const int kh = hq / 7;
  const int t0w = (w < 2) ? ((31 - p) * 64 + w * 32) : (p * 64 + (w - 2) * 32);
  const int myN = (t0w >> 6) + 1;   // KV tiles this wave needs
  const int nIt = 32 - p;           // block-level iterations (heavy wave's count)

  // Q B-frags, pre-scaled by (1/sqrt(128))*log2(e): lane holds Q[q][cc*16 + h*8 + j]
  const float qs = 0.12751744f;
  bf16x8 qf[8];
  {
    const ushort* qrow = QKV + (size_t)(t0w + q) * QKV_N + hq * 128;
#pragma unroll
    for (int cc = 0; cc < 8; ++cc) {
      bf16x8 v = *(const bf16x8*)(qrow + cc * 16 + h * 8);
#pragma unroll
      for (int j = 0; j < 8; ++j) v[j] = (__bf16)((float)v[j] * qs);
      qf[cc] = v;
    }
  }

  f32x16 acc[4];
#pragma unroll
  for (int db = 0; db < 4; ++db) acc[db] = f32x16{};
  float m = -3e38f, lsum = 0.f;

  const size_t kbyte0 = (size_t)(H_DIM + kh * 128) * 2;
  const ushort* VTh = VT + (size_t)kh * 128 * T_SEQ;

  auto stage = [&](int buf, int s0) {
#pragma unroll
    for (int rnd = 0; rnd < 4; ++rnd) {
      int d = rnd * 4096 + tid * 16;  // dest byte in 16KB tile
      int r = d >> 8;                 // s-row
      int cb = d & 255;               // byte within row
      const char* src = (const char*)QKV + (size_t)(s0 + r) * (QKV_N * 2) + kbyte0 +
                        (cb ^ ((r & 15) << 4));
      gload_lds16(src, (char*)Ksm[buf] + rnd * 4096 + w * 1024);
    }
  };

  stage(0, 0);
  for (int sb = 0; sb < nIt; ++sb) {
    __syncthreads();  // buf[sb&1] ready; everyone done with buf[(sb+1)&1]
    if (sb + 1 < nIt) stage((sb + 1) & 1, (sb + 1) * 64);
    if (sb >= myN) continue;  // light waves idle (still stage + barrier)

    // ---- V A-frags direct from L2 (independent: issue early) ----
    bf16x8 vf[4][4];
#pragma unroll
    for (int db = 0; db < 4; ++db)
#pragma unroll
      for (int c = 0; c < 4; ++c)
        vf[db][c] = *(const bf16x8*)(VTh + (size_t)(db * 32 + q) * T_SEQ + sb * 64 + c * 16 + h * 8);

    // ---- S^T(64 kpos x 32 q) = K @ Q^T : two 32x32 subtiles ----
    const char* Kb = Ksm[sb & 1];
    const int swz = (q & 15) << 4;
    f32x16 sa0 = {}, sa1 = {};
#pragma unroll
    for (int cc = 0; cc < 8; ++cc) {
      int colb = (cc * 32 + h * 16) ^ swz;
      bf16x8 kf0 = *(const bf16x8*)(Kb + q * 256 + colb);
      bf16x8 kf1 = *(const bf16x8*)(Kb + (32 + q) * 256 + colb);
      sa0 = __builtin_amdgcn_mfma_f32_32x32x16_bf16(kf0, qf[cc], sa0, 0, 0, 0);
      sa1 = __builtin_amdgcn_mfma_f32_32x32x16_bf16(kf1, qf[cc], sa1, 0, 0, 0);
    }

    // ---- causal mask (only on this wave's last tile) ----
    if (sb == myN - 1) {
      const int t = t0w + q;
#pragma unroll
      for (int r = 0; r < 16; ++r) {
        int kl = (r & 3) + 8 * (r >> 2) + 4 * h;
        if (sb * 64 + kl > t) sa0[r] = -1e30f;
        if (sb * 64 + 32 + kl > t) sa1[r] = -1e30f;
      }
    }

    // ---- in-lane softmax (log2 units), defer-max THR=8 ----
    float pmax = -3e38f;
#pragma unroll
    for (int r = 0; r < 16; ++r) pmax = fmaxf(pmax, fmaxf(sa0[r], sa1[r]));
    pmax = fmaxf(pmax, __shfl_xor(pmax, 32, 64));
    if (__any(pmax > m + 8.f)) {
      float mn = fmaxf(m, pmax);
      float rs = EXP2(m - mn);
      m = mn;
      lsum *= rs;
#pragma unroll
      for (int db = 0; db < 4; ++db)
#pragma unroll
        for (int r = 0; r < 16; ++r) acc[db][r] *= rs;
    }
    float psum = 0.f;
#pragma unroll
    for (int r = 0; r < 16; ++r) { sa0[r] = EXP2(sa0[r] - m); psum += sa0[r]; }
#pragma unroll
    for (int r = 0; r < 16; ++r) { sa1[r] = EXP2(sa1[r] - m); psum += sa1[r]; }
    lsum += psum;  // per-half partial; combined at epilogue

    // ---- P -> bf16 B-frags (cvt_pk + permlane32_swap), PV: acc = V^T @ P^T ----
#pragma unroll
    for (int c = 0; c < 4; ++c) {
      const f32x16& P = (c < 2) ? sa0 : sa1;
      const int e = c & 1;
      uint a0 = cvtpk(P[8 * e + 0], P[8 * e + 1]);
      uint a1 = cvtpk(P[8 * e + 2], P[8 * e + 3]);
      uint a2 = cvtpk(P[8 * e + 4], P[8 * e + 5]);
      uint a3 = cvtpk(P[8 * e + 6], P[8 * e + 7]);
      swap32(a0, a2);  // a0 = w0, a2 = w2
      swap32(a1, a3);  // a1 = w1, a3 = w3
      u32x4 pw = {a0, a1, a2, a3};
      bf16x8 pf = __builtin_bit_cast(bf16x8, pw);
#pragma unroll
      for (int db = 0; db < 4; ++db)
        acc[db] = __builtin_amdgcn_mfma_f32_32x32x16_bf16(vf[db][c], pf, acc[db], 0, 0, 0);
    }
  }

  // ---- epilogue: combine lsum halves, normalize, store ----
  float lt = lsum + __shfl_xor(lsum, 32, 64);
  float inv = 1.f / lt;
  ushort* orow = O + (size_t)(t0w + q) * H_DIM + hq * 128;
#pragma unroll
  for (int db = 0; db < 4; ++db) {
#pragma unroll
    for (int rg = 0; rg < 4; ++rg) {
      ushort4 o;
      o.x = f2b(acc[db][rg * 4 + 0] * inv);
      o.y = f2b(acc[db][rg * 4 + 1] * inv);
      o.z = f2b(acc[db][rg * 4 + 2] * inv);
      o.w = f2b(acc[db][rg * 4 + 3] * inv);
      *(ushort4*)(orow + db * 32 + rg * 8 + h * 4) = o;
    }
  }
}

extern "C" void kernel_launch(void* const* d_in, const int* in_sizes, int n_in,
                              void* d_out, int out_size, void* d_ws, size_t ws_size,
                              hipStream_t stream) {
  const float* hs = (const float*)d_in[0];
  const int* pos = (const int*)d_in[1];
  const float* Wq = (const float*)d_in[2];
  const float* bq = (const float*)d_in[3];
  const float* Wk = (const float*)d_in[4];
  const float* bk = (const float*)d_in[5];
  const float* Wv = (const float*)d_in[6];
  const float* bv = (const float*)d_in[7];
  const float* Wo = (const float*)d_in[8];
  float* out = (float*)d_out;

  char* p = (char*)d_ws;
  ushort* hs_b = (ushort*)p;  p += (size_t)T_SEQ * H_DIM * 2;
  ushort* WqkvT = (ushort*)p; p += (size_t)QKV_N * H_DIM * 2;
  ushort* WoT = (ushort*)p;   p += (size_t)H_DIM * H_DIM * 2;
  float* biasb = (float*)p;   p += (size_t)QKV_N * 4;
  ushort* QKV = (ushort*)p;   p += (size_t)T_SEQ * QKV_N * 2;
  ushort* VT = (ushort*)p;    p += (size_t)NKVH * HD * T_SEQ * 2;
  ushort* Obuf = (ushort*)p;  p += (size_t)T_SEQ * H_DIM * 2;

  cast_bf16_kernel<<<T_SEQ * H_DIM / 1024, 256, 0, stream>>>(hs, hs_b);
  transpose_cast_kernel<<<dim3(H_DIM / 32, H_DIM / 32), dim3(32, 8), 0, stream>>>(Wq, WqkvT, H_DIM, H_DIM);
  transpose_cast_kernel<<<dim3(KV_N / 32, H_DIM / 32), dim3(32, 8), 0, stream>>>(
      Wk, WqkvT + (size_t)H_DIM * H_DIM, H_DIM, KV_N);
  transpose_cast_kernel<<<dim3(KV_N / 32, H_DIM / 32), dim3(32, 8), 0, stream>>>(
      Wv, WqkvT + (size_t)(H_DIM + KV_N) * H_DIM, H_DIM, KV_N);
  transpose_cast_kernel<<<dim3(H_DIM / 32, H_DIM / 32), dim3(32, 8), 0, stream>>>(Wo, WoT, H_DIM, H_DIM);
  concat_bias_kernel<<<QKV_N / 256, 256, 0, stream>>>(bq, bk, bv, biasb);
  gemm256_kernel<1><<<dim3(QKV_N / 256, T_SEQ / 256), 512, 0, stream>>>(
      hs_b, WqkvT, biasb, QKV, T_SEQ, QKV_N, K_DIM);
  rope_kernel<<<T_SEQ, 256, 0, stream>>>(QKV, pos);
  build_vt_kernel<<<dim3(HD / 32, T_SEQ / 32, NKVH), dim3(32, 8), 0, stream>>>(QKV, VT);
  attn_kernel<<<dim3(16, NQH), 256, 0, stream>>>(QKV, VT, Obuf);
  gemm256_kernel<0><<<dim3(H_DIM / 256, T_SEQ / 256), 512, 0, stream>>>(
      Obuf, WoT, nullptr, out, T_SEQ, H_DIM, K_DIM);
}

// Round 5
// 308.644 us; speedup vs baseline: 2.0330x; 1.1878x over previous
//
#include <hip/hip_runtime.h>
#include <hip/hip_bf16.h>
#include <stdint.h>

#define T_SEQ 2048
#define H_DIM 3584
#define NQH 28
#define NKVH 4
#define HD 128
#define KV_N 512          // NKVH*HD
#define QKV_N 4608        // 3584 + 512 + 512
#define K_DIM 3584

typedef __bf16 bf16x8 __attribute__((ext_vector_type(8)));
typedef float f32x4 __attribute__((ext_vector_type(4)));
typedef float f32x16 __attribute__((ext_vector_type(16)));
typedef uint u32x4 __attribute__((ext_vector_type(4)));

#if __has_builtin(__builtin_amdgcn_exp2f)
#define EXP2 __builtin_amdgcn_exp2f
#else
#define EXP2 exp2f
#endif

__device__ __forceinline__ ushort f2b(float f) {
  uint x = __builtin_bit_cast(uint, f);
  x += 0x7fffu + ((x >> 16) & 1u);
  return (ushort)(x >> 16);
}
__device__ __forceinline__ float b2f(ushort u) {
  return __builtin_bit_cast(float, (uint)u << 16);
}

__device__ __forceinline__ void gload_lds16(const void* gptr, void* ldsptr) {
  __builtin_amdgcn_global_load_lds(
      (const __attribute__((address_space(1))) uint32_t*)gptr,
      (__attribute__((address_space(3))) uint32_t*)ldsptr, 16, 0, 0);
}

#define FULL_BARRIER()                              \
  do {                                              \
    asm volatile("" ::: "memory");                  \
    __builtin_amdgcn_s_barrier();                   \
    asm volatile("" ::: "memory");                  \
  } while (0)

template <int N>
__device__ __forceinline__ void waitcnt_vm() {
  if constexpr (N == 0) asm volatile("s_waitcnt vmcnt(0)" ::: "memory");
  else if constexpr (N == 6) asm volatile("s_waitcnt vmcnt(6)" ::: "memory");
  else if constexpr (N == 8) asm volatile("s_waitcnt vmcnt(8)" ::: "memory");
  else static_assert(N == 0 || N == 6 || N == 8, "unsupported vmcnt");
}

// pack two f32 -> one u32 of 2 bf16 (lo = a, hi = b)
__device__ __forceinline__ uint cvtpk(float a, float b) {
  uint r;
  asm("v_cvt_pk_bf16_f32 %0, %1, %2" : "=v"(r) : "v"(a), "v"(b));
  return r;
}
__device__ __forceinline__ void swap32(uint& a, uint& b) {
#if __has_builtin(__builtin_amdgcn_permlane32_swap)
  typedef int i32x2 __attribute__((ext_vector_type(2)));
  i32x2 r = __builtin_amdgcn_permlane32_swap((int)a, (int)b, false, false);
  a = (uint)r.x; b = (uint)r.y;
#else
  int lo = ((threadIdx.x & 63) < 32);
  uint sa = __shfl_xor((int)a, 32, 64);
  uint sb = __shfl_xor((int)b, 32, 64);
  uint na = lo ? a : sb;
  uint nb = lo ? sa : b;
  a = na; b = nb;
#endif
}

// ---------------- cast hidden fp32 -> bf16 ----------------
__global__ void cast_bf16_kernel(const float* __restrict__ in, ushort* __restrict__ out) {
  int i = (blockIdx.x * 256 + threadIdx.x) * 4;
  float4 v = *(const float4*)(in + i);
  ushort4 o = make_ushort4(f2b(v.x), f2b(v.y), f2b(v.z), f2b(v.w));
  *(ushort4*)(out + i) = o;
}

// ---------------- transpose + cast: W (K x N) fp32 -> WT (N x K) bf16 ----------------
__global__ void transpose_cast_kernel(const float* __restrict__ W, ushort* __restrict__ WT,
                                      int K, int N) {
  __shared__ float tile[32][33];
  int n0 = blockIdx.x * 32, k0 = blockIdx.y * 32;
  int tx = threadIdx.x, ty = threadIdx.y;  // 32 x 8
#pragma unroll
  for (int j = 0; j < 4; ++j)
    tile[ty + j * 8][tx] = W[(size_t)(k0 + ty + j * 8) * N + n0 + tx];
  __syncthreads();
#pragma unroll
  for (int j = 0; j < 4; ++j)
    WT[(size_t)(n0 + ty + j * 8) * K + k0 + tx] = f2b(tile[tx][ty + j * 8]);
}

// ---------------- bias concat [bq | bk | bv] ----------------
__global__ void concat_bias_kernel(const float* __restrict__ bq, const float* __restrict__ bk,
                                   const float* __restrict__ bv, float* __restrict__ out) {
  int i = blockIdx.x * 256 + threadIdx.x;
  float v;
  if (i < H_DIM) v = bq[i];
  else if (i < H_DIM + KV_N) v = bk[i - H_DIM];
  else v = bv[i - H_DIM - KV_N];
  out[i] = v;
}

// ---------------- generic phase-pipelined GEMM ----------------
// C[r, c] = A(MxK) @ B, with BT given as (N x K) bf16. Tile BM x BN, BK=64.
// Waves: (BM/64) x (BN/64), each wave owns a 64x64 out tile (4x4 frags).
// 3 LDS slots, prefetch distance 2 tiles, counted vmcnt(LA+LB) at boundary.
// LDS reads XOR-swizzled (granule ^= row&7); staging source pre-swizzled
// with the same involution (global_load_lds dest stays linear).
template <int BM, int BN, int OUT_MODE>
__global__ __launch_bounds__((BM / 64) * (BN / 64) * 64, (BM / 64) * (BN / 64) / 4)
void gemm_pipe_kernel(const ushort* __restrict__ A, const ushort* __restrict__ BT,
                      const float* __restrict__ bias, void* __restrict__ Cout,
                      int ldC, int K) {
  constexpr int WM = BM / 64, WN = BN / 64;
  constexpr int T = WM * WN * 64;
  constexpr int LA = BM * 8 / T;   // 16B loads/thread for a BMx64 A-tile
  constexpr int LB = BN * 8 / T;
  constexpr int LT = LA + LB;
  __shared__ __align__(16) ushort As[3][BM * 64];
  __shared__ __align__(16) ushort Bs[3][BN * 64];
  const int tid = threadIdx.x;
  const int lane = tid & 63;
  const int w = tid >> 6;
  const int wr = w / WN, wc = w % WN;
  const int g4 = lane >> 4, l16 = lane & 15;
  const int r0 = blockIdx.y * BM, c0 = blockIdx.x * BN;
  const int nk = K >> 6;

  f32x4 acc[4][4];
#pragma unroll
  for (int a = 0; a < 4; ++a)
#pragma unroll
    for (int b = 0; b < 4; ++b) acc[a][b] = f32x4{0.f, 0.f, 0.f, 0.f};

  // stage half of tile t's A (LA/2 loads) into slot s
  auto stageA = [&](int s, int t, int half) {
#pragma unroll
    for (int j = 0; j < LA / 2; ++j) {
      int idx = (half * (LA / 2) + j) * T + tid;  // granule index
      int row = idx >> 3;                          // 8 granules per 128B row
      int g = idx & 7;
      const ushort* src = A + (size_t)(r0 + row) * K + t * 64 + (g ^ (row & 7)) * 8;
      gload_lds16(src, (char*)As[s] + idx * 16);
    }
  };
  auto stageB = [&](int s, int t, int half) {
#pragma unroll
    for (int j = 0; j < LB / 2; ++j) {
      int idx = (half * (LB / 2) + j) * T + tid;
      int row = idx >> 3;
      int g = idx & 7;
      const ushort* src = BT + (size_t)(c0 + row) * K + t * 64 + (g ^ (row & 7)) * 8;
      gload_lds16(src, (char*)Bs[s] + idx * 16);
    }
  };

  // prologue: tiles 0 and 1; wait for tile 0 (tile 1's LT loads stay in flight)
  stageA(0, 0, 0); stageA(0, 0, 1); stageB(0, 0, 0); stageB(0, 0, 1);
  stageA(1, 1, 0); stageA(1, 1, 1); stageB(1, 1, 0); stageB(1, 1, 1);
  waitcnt_vm<LT>();
  FULL_BARRIER();

  for (int t = 0; t < nk; ++t) {
    const int s = t % 3;
    const int sp = (t + 2) % 3;
    const bool pf = (t + 2 < nk);
    const char* Asl = (const char*)As[s];
    const char* Bsl = (const char*)Bs[s];

#pragma unroll
    for (int kk = 0; kk < 2; ++kk) {
      bf16x8 af[4], bf[4];
#pragma unroll
      for (int mi = 0; mi < 4; ++mi) {
        int row = wr * 64 + mi * 16 + l16;
        int g = (kk * 4 + g4) ^ (row & 7);
        af[mi] = *(const bf16x8*)(Asl + row * 128 + g * 16);
      }
#pragma unroll
      for (int ni = 0; ni < 4; ++ni) {
        int row = wc * 64 + ni * 16 + l16;
        int g = (kk * 4 + g4) ^ (row & 7);
        bf[ni] = *(const bf16x8*)(Bsl + row * 128 + g * 16);
      }
      if (pf) { stageA(sp, t + 2, kk); stageB(sp, t + 2, kk); }
      __builtin_amdgcn_sched_barrier(0);
      FULL_BARRIER();
      asm volatile("s_waitcnt lgkmcnt(0)" ::: "memory");
      __builtin_amdgcn_sched_barrier(0);
      __builtin_amdgcn_s_setprio(1);
#pragma unroll
      for (int mi = 0; mi < 4; ++mi)
#pragma unroll
        for (int ni = 0; ni < 4; ++ni)
          acc[mi][ni] = __builtin_amdgcn_mfma_f32_16x16x32_bf16(af[mi], bf[ni], acc[mi][ni], 0, 0, 0);
      __builtin_amdgcn_s_setprio(0);
      __builtin_amdgcn_sched_barrier(0);
      if (kk == 1 && t + 1 < nk) {
        if (pf) waitcnt_vm<LT>();
        else    waitcnt_vm<0>();
      }
      FULL_BARRIER();
    }
  }

  // epilogue: D row=(lane>>4)*4+i within frag, col=lane&15
#pragma unroll
  for (int mi = 0; mi < 4; ++mi) {
#pragma unroll
    for (int ni = 0; ni < 4; ++ni) {
      int col = c0 + wc * 64 + ni * 16 + l16;
      float bv = (OUT_MODE == 1) ? bias[col] : 0.f;
#pragma unroll
      for (int i = 0; i < 4; ++i) {
        int row = r0 + wr * 64 + mi * 16 + g4 * 4 + i;
        float v = acc[mi][ni][i] + bv;
        if (OUT_MODE == 1)
          ((ushort*)Cout)[(size_t)row * ldC + col] = f2b(v);
        else
          ((float*)Cout)[(size_t)row * ldC + col] = v;
      }
    }
  }
}

// ---------------- RoPE in-place on QKV (q heads 0..27, k heads 28..31) ----------------
__global__ void rope_kernel(ushort* __restrict__ QKV, const int* __restrict__ pos_ids) {
  int t = blockIdx.x;
  float pos = (float)pos_ids[t];
  ushort* row = QKV + (size_t)t * QKV_N;
  for (int p = threadIdx.x; p < 2048; p += 256) {  // 32 heads * 64 pairs
    int head = p >> 6;
    int d = p & 63;
    float inv = expf(-0.2158673524f * (float)d);  // theta^(-d/64), ln(1e6)/64
    float fr = pos * inv;
    float s, c;
    sincosf(fr, &s, &c);
    int c1 = head * 128 + d, c2 = c1 + 64;
    float x1 = b2f(row[c1]), x2 = b2f(row[c2]);
    row[c1] = f2b(x1 * c - x2 * s);
    row[c2] = f2b(x2 * c + x1 * s);
  }
}

// ---------------- build VT[kh][d][s] from QKV v-part ----------------
__global__ void build_vt_kernel(const ushort* __restrict__ QKV, ushort* __restrict__ VT) {
  __shared__ ushort tile[32][33];
  int kh = blockIdx.z;
  int d0 = blockIdx.x * 32, s0 = blockIdx.y * 32;
  int tx = threadIdx.x, ty = threadIdx.y;
#pragma unroll
  for (int j = 0; j < 4; ++j)
    tile[ty + j * 8][tx] =
        QKV[(size_t)(s0 + ty + j * 8) * QKV_N + (H_DIM + KV_N) + kh * 128 + d0 + tx];
  __syncthreads();
#pragma unroll
  for (int j = 0; j < 4; ++j)
    VT[((size_t)kh * 128 + d0 + ty + j * 8) * T_SEQ + s0 + tx] = tile[tx][ty + j * 8];
}

// ---------------- flash attention v3: swapped-QK^T, in-register softmax ----------------
__global__ __launch_bounds__(256, 2) void attn_kernel(const ushort* __restrict__ QKV,
                                                      const ushort* __restrict__ VT,
                                                      ushort* __restrict__ O) {
  __shared__ __align__(16) char Ksm[2][16384];  // 64 s-rows x 256B (128 d bf16), swizzled
  const int tid = threadIdx.x;
  const int lane = tid & 63;
  const int w = tid >> 6;
  const int q = lane & 31;       // q-row / kpos-local / d-local lane field
  const int h = lane >> 5;       // half selector
  const int p = blockIdx.x;      // pair index 0..15
  const int hq = blockIdx.y;     // q-head
  const int kh = hq / 7;
  const int t0w = (w < 2) ? ((31 - p) * 64 + w * 32) : (p * 64 + (w - 2) * 32);
  const int myN = (t0w >> 6) + 1;   // KV tiles this wave needs
  const int nIt = 32 - p;           // block-level iterations (heavy wave's count)

  // Q B-frags, pre-scaled by (1/sqrt(128))*log2(e): lane holds Q[q][cc*16 + h*8 + j]
  const float qs = 0.12751744f;
  bf16x8 qf[8];
  {
    const ushort* qrow = QKV + (size_t)(t0w + q) * QKV_N + hq * 128;
#pragma unroll
    for (int cc = 0; cc < 8; ++cc) {
      bf16x8 v = *(const bf16x8*)(qrow + cc * 16 + h * 8);
#pragma unroll
      for (int j = 0; j < 8; ++j) v[j] = (__bf16)((float)v[j] * qs);
      qf[cc] = v;
    }
  }

  f32x16 acc[4];
#pragma unroll
  for (int db = 0; db < 4; ++db) acc[db] = f32x16{};
  float m = -3e38f, lsum = 0.f;

  const size_t kbyte0 = (size_t)(H_DIM + kh * 128) * 2;
  const ushort* VTh = VT + (size_t)kh * 128 * T_SEQ;

  auto stage = [&](int buf, int s0) {
#pragma unroll
    for (int rnd = 0; rnd < 4; ++rnd) {
      int d = rnd * 4096 + tid * 16;  // dest byte in 16KB tile
      int r = d >> 8;                 // s-row
      int cb = d & 255;               // byte within row
      const char* src = (const char*)QKV + (size_t)(s0 + r) * (QKV_N * 2) + kbyte0 +
                        (cb ^ ((r & 15) << 4));
      gload_lds16(src, (char*)Ksm[buf] + rnd * 4096 + w * 1024);
    }
  };

  stage(0, 0);
  for (int sb = 0; sb < nIt; ++sb) {
    __syncthreads();  // buf[sb&1] ready; everyone done with buf[(sb+1)&1]
    if (sb + 1 < nIt) stage((sb + 1) & 1, (sb + 1) * 64);
    if (sb >= myN) continue;  // light waves idle (still stage + barrier)

    // ---- V A-frags direct from L2 (independent: issue early) ----
    bf16x8 vf[4][4];
#pragma unroll
    for (int db = 0; db < 4; ++db)
#pragma unroll
      for (int c = 0; c < 4; ++c)
        vf[db][c] = *(const bf16x8*)(VTh + (size_t)(db * 32 + q) * T_SEQ + sb * 64 + c * 16 + h * 8);

    // ---- S^T(64 kpos x 32 q) = K @ Q^T : two 32x32 subtiles ----
    const char* Kb = Ksm[sb & 1];
    const int swz = (q & 15) << 4;
    f32x16 sa0 = {}, sa1 = {};
#pragma unroll
    for (int cc = 0; cc < 8; ++cc) {
      int colb = (cc * 32 + h * 16) ^ swz;
      bf16x8 kf0 = *(const bf16x8*)(Kb + q * 256 + colb);
      bf16x8 kf1 = *(const bf16x8*)(Kb + (32 + q) * 256 + colb);
      sa0 = __builtin_amdgcn_mfma_f32_32x32x16_bf16(kf0, qf[cc], sa0, 0, 0, 0);
      sa1 = __builtin_amdgcn_mfma_f32_32x32x16_bf16(kf1, qf[cc], sa1, 0, 0, 0);
    }

    // ---- causal mask (only on this wave's last tile) ----
    if (sb == myN - 1) {
      const int t = t0w + q;
#pragma unroll
      for (int r = 0; r < 16; ++r) {
        int kl = (r & 3) + 8 * (r >> 2) + 4 * h;
        if (sb * 64 + kl > t) sa0[r] = -1e30f;
        if (sb * 64 + 32 + kl > t) sa1[r] = -1e30f;
      }
    }

    // ---- in-lane softmax (log2 units), defer-max THR=8 ----
    float pmax = -3e38f;
#pragma unroll
    for (int r = 0; r < 16; ++r) pmax = fmaxf(pmax, fmaxf(sa0[r], sa1[r]));
    pmax = fmaxf(pmax, __shfl_xor(pmax, 32, 64));
    if (__any(pmax > m + 8.f)) {
      float mn = fmaxf(m, pmax);
      float rs = EXP2(m - mn);
      m = mn;
      lsum *= rs;
#pragma unroll
      for (int db = 0; db < 4; ++db)
#pragma unroll
        for (int r = 0; r < 16; ++r) acc[db][r] *= rs;
    }
    float psum = 0.f;
#pragma unroll
    for (int r = 0; r < 16; ++r) { sa0[r] = EXP2(sa0[r] - m); psum += sa0[r]; }
#pragma unroll
    for (int r = 0; r < 16; ++r) { sa1[r] = EXP2(sa1[r] - m); psum += sa1[r]; }
    lsum += psum;  // per-half partial; combined at epilogue

    // ---- P -> bf16 B-frags (cvt_pk + permlane32_swap), PV: acc = V^T @ P^T ----
#pragma unroll
    for (int c = 0; c < 4; ++c) {
      const f32x16& P = (c < 2) ? sa0 : sa1;
      const int e = c & 1;
      uint a0 = cvtpk(P[8 * e + 0], P[8 * e + 1]);
      uint a1 = cvtpk(P[8 * e + 2], P[8 * e + 3]);
      uint a2 = cvtpk(P[8 * e + 4], P[8 * e + 5]);
      uint a3 = cvtpk(P[8 * e + 6], P[8 * e + 7]);
      swap32(a0, a2);  // a0 = w0, a2 = w2
      swap32(a1, a3);  // a1 = w1, a3 = w3
      u32x4 pw = {a0, a1, a2, a3};
      bf16x8 pf = __builtin_bit_cast(bf16x8, pw);
#pragma unroll
      for (int db = 0; db < 4; ++db)
        acc[db] = __builtin_amdgcn_mfma_f32_32x32x16_bf16(vf[db][c], pf, acc[db], 0, 0, 0);
    }
  }

  // ---- epilogue: combine lsum halves, normalize, store ----
  float lt = lsum + __shfl_xor(lsum, 32, 64);
  float inv = 1.f / lt;
  ushort* orow = O + (size_t)(t0w + q) * H_DIM + hq * 128;
#pragma unroll
  for (int db = 0; db < 4; ++db) {
#pragma unroll
    for (int rg = 0; rg < 4; ++rg) {
      ushort4 o;
      o.x = f2b(acc[db][rg * 4 + 0] * inv);
      o.y = f2b(acc[db][rg * 4 + 1] * inv);
      o.z = f2b(acc[db][rg * 4 + 2] * inv);
      o.w = f2b(acc[db][rg * 4 + 3] * inv);
      *(ushort4*)(orow + db * 32 + rg * 8 + h * 4) = o;
    }
  }
}

extern "C" void kernel_launch(void* const* d_in, const int* in_sizes, int n_in,
                              void* d_out, int out_size, void* d_ws, size_t ws_size,
                              hipStream_t stream) {
  const float* hs = (const float*)d_in[0];
  const int* pos = (const int*)d_in[1];
  const float* Wq = (const float*)d_in[2];
  const float* bq = (const float*)d_in[3];
  const float* Wk = (const float*)d_in[4];
  const float* bk = (const float*)d_in[5];
  const float* Wv = (const float*)d_in[6];
  const float* bv = (const float*)d_in[7];
  const float* Wo = (const float*)d_in[8];
  float* out = (float*)d_out;

  char* p = (char*)d_ws;
  ushort* hs_b = (ushort*)p;  p += (size_t)T_SEQ * H_DIM * 2;
  ushort* WqkvT = (ushort*)p; p += (size_t)QKV_N * H_DIM * 2;
  ushort* WoT = (ushort*)p;   p += (size_t)H_DIM * H_DIM * 2;
  float* biasb = (float*)p;   p += (size_t)QKV_N * 4;
  ushort* QKV = (ushort*)p;   p += (size_t)T_SEQ * QKV_N * 2;
  ushort* VT = (ushort*)p;    p += (size_t)NKVH * HD * T_SEQ * 2;
  ushort* Obuf = (ushort*)p;  p += (size_t)T_SEQ * H_DIM * 2;

  cast_bf16_kernel<<<T_SEQ * H_DIM / 1024, 256, 0, stream>>>(hs, hs_b);
  transpose_cast_kernel<<<dim3(H_DIM / 32, H_DIM / 32), dim3(32, 8), 0, stream>>>(Wq, WqkvT, H_DIM, H_DIM);
  transpose_cast_kernel<<<dim3(KV_N / 32, H_DIM / 32), dim3(32, 8), 0, stream>>>(
      Wk, WqkvT + (size_t)H_DIM * H_DIM, H_DIM, KV_N);
  transpose_cast_kernel<<<dim3(KV_N / 32, H_DIM / 32), dim3(32, 8), 0, stream>>>(
      Wv, WqkvT + (size_t)(H_DIM + KV_N) * H_DIM, H_DIM, KV_N);
  transpose_cast_kernel<<<dim3(H_DIM / 32, H_DIM / 32), dim3(32, 8), 0, stream>>>(Wo, WoT, H_DIM, H_DIM);
  concat_bias_kernel<<<QKV_N / 256, 256, 0, stream>>>(bq, bk, bv, biasb);

  // Q-projection: C[:, 0:3584] of QKV (224 blocks, 87.5% CU util)
  gemm_pipe_kernel<256, 128, 1><<<dim3(H_DIM / 128, T_SEQ / 256), 512, 0, stream>>>(
      hs_b, WqkvT, biasb, QKV, QKV_N, K_DIM);
  // KV-projection: C[:, 3584:4608] (128 blocks)
  gemm_pipe_kernel<128, 128, 1><<<dim3((2 * KV_N) / 128, T_SEQ / 128), 256, 0, stream>>>(
      hs_b, WqkvT + (size_t)H_DIM * K_DIM, biasb + H_DIM, QKV + H_DIM, QKV_N, K_DIM);

  rope_kernel<<<T_SEQ, 256, 0, stream>>>(QKV, pos);
  build_vt_kernel<<<dim3(HD / 32, T_SEQ / 32, NKVH), dim3(32, 8), 0, stream>>>(QKV, VT);
  attn_kernel<<<dim3(16, NQH), 256, 0, stream>>>(QKV, VT, Obuf);

  // output projection (224 blocks)
  gemm_pipe_kernel<256, 128, 0><<<dim3(H_DIM / 128, T_SEQ / 256), 512, 0, stream>>>(
      Obuf, WoT, nullptr, out, H_DIM, K_DIM);
}